// Round 6
// baseline (1073.371 us; speedup 1.0000x reference)
//
#include <hip/hip_runtime.h>

#define HID 128
#define EPSF 1e-6f

__device__ inline unsigned f2bf(float f) {
  unsigned u = __float_as_uint(f);
  return (u + 0x7fffu + ((u >> 16) & 1u)) >> 16;  // RNE
}

// ---------------- fused histogram of x (65 bins) + per-row edge count ----------------
__global__ void k_histcnt(const int* __restrict__ x, int n, const int* __restrict__ row,
                          int e, int* __restrict__ hist, int* __restrict__ cnt) {
  __shared__ int lh[65];
  int t = threadIdx.x;
  if (t < 65) lh[t] = 0;
  __syncthreads();
  int tid = blockIdx.x * blockDim.x + t, stride = gridDim.x * blockDim.x;
  for (int i = tid; i < e; i += stride) atomicAdd(&cnt[row[i]], 1);
  for (int i = tid; i < n; i += stride) atomicAdd(&lh[x[i]], 1);
  __syncthreads();
  if (t < 65 && lh[t]) atomicAdd(&hist[t], lh[t]);
}

// ---------------- 3-phase exclusive scan over cnt[0..n) -> rowptr ----------------
__global__ void k_scan_partial(const int* __restrict__ cnt, int n, int* __restrict__ bsum) {
  __shared__ int sh[256];
  int t = threadIdx.x;
  int base = blockIdx.x * 2048 + t * 8;
  int s = 0;
#pragma unroll
  for (int j = 0; j < 8; ++j) { int idx = base + j; if (idx < n) s += cnt[idx]; }
  sh[t] = s; __syncthreads();
  for (int off = 128; off > 0; off >>= 1) {
    if (t < off) sh[t] += sh[t + off];
    __syncthreads();
  }
  if (t == 0) bsum[blockIdx.x] = sh[0];
}

__global__ void k_scan_bsum(int* __restrict__ bsum, int nb) {
  if (threadIdx.x == 0 && blockIdx.x == 0) {
    int acc = 0;
    for (int i = 0; i < nb; ++i) { int v = bsum[i]; bsum[i] = acc; acc += v; }
  }
}

__global__ void k_scan_final(const int* __restrict__ cnt, int n, const int* __restrict__ bsum,
                             int* __restrict__ rowptr, int* __restrict__ cursor) {
  __shared__ int sh[256];
  int t = threadIdx.x;
  int base = blockIdx.x * 2048 + t * 8;
  int v[8]; int s = 0;
#pragma unroll
  for (int j = 0; j < 8; ++j) { int idx = base + j; v[j] = (idx < n) ? cnt[idx] : 0; s += v[j]; }
  sh[t] = s; __syncthreads();
  for (int off = 1; off < 256; off <<= 1) {
    int val = (t >= off) ? sh[t - off] : 0;
    __syncthreads();
    sh[t] += val;
    __syncthreads();
  }
  int off0 = bsum[blockIdx.x] + sh[t] - s;  // exclusive prefix for this thread
#pragma unroll
  for (int j = 0; j < 8; ++j) {
    int idx = base + j;
    if (idx < n) { rowptr[idx] = off0; cursor[idx] = off0; off0 += v[j]; }
  }
}

// ---------------- scatter edges into CSR order: ({col | x<<17}, ew), 4-deep MLP ------
__global__ __launch_bounds__(256) void k_scatter(
    const int* __restrict__ row, const int* __restrict__ col,
    const float* __restrict__ ew, const int* __restrict__ x, int e,
    int* __restrict__ cursor, int2* __restrict__ sedge) {
  int tid = blockIdx.x * blockDim.x + threadIdx.x;
  int stride = gridDim.x * blockDim.x;
  for (int i0 = tid; i0 < e; i0 += stride * 4) {
    int r[4], c[4], xc[4], idx[4]; float w[4]; bool valid[4];
#pragma unroll
    for (int k = 0; k < 4; ++k) {
      int i = i0 + k * stride; valid[k] = (i < e);
      if (valid[k]) { r[k] = row[i]; c[k] = col[i]; w[k] = ew[i]; }
    }
#pragma unroll
    for (int k = 0; k < 4; ++k) if (valid[k]) xc[k] = x[c[k]];
#pragma unroll
    for (int k = 0; k < 4; ++k) if (valid[k]) idx[k] = atomicAdd(&cursor[r[k]], 1);
#pragma unroll
    for (int k = 0; k < 4; ++k)
      if (valid[k]) sedge[idx[k]] = make_int2(c[k] | (xc[k] << 17), __float_as_int(w[k]));
  }
}

// ---------------- fold GN0 into bf16-packed embedding table ----------------
__global__ void k_gn0(const float* __restrict__ emb, const int* __restrict__ hist,
                      const float* __restrict__ gw, const float* __restrict__ gb,
                      const float* __restrict__ gms, float invN,
                      unsigned* __restrict__ emb1b) {
  int t = threadIdx.x;  // 64 threads; cols d0=2t, d1=2t+1
  int d0 = t * 2, d1 = t * 2 + 1;
  float s0 = 0, s20 = 0, s1 = 0, s21 = 0;
  for (int k = 0; k < 65; ++k) {
    float c = (float)hist[k];
    float v0 = emb[k * HID + d0], v1 = emb[k * HID + d1];
    s0 += c * v0; s20 += c * v0 * v0;
    s1 += c * v1; s21 += c * v1 * v1;
  }
  float m0 = s0 * invN, E20 = s20 * invN;
  float m1 = s1 * invN, E21 = s21 * invN;
  float sh0 = m0 * gms[d0], sh1 = m1 * gms[d1];
  float aa0 = gw[d0] / sqrtf(E20 - 2.f * sh0 * m0 + sh0 * sh0 + EPSF);
  float aa1 = gw[d1] / sqrtf(E21 - 2.f * sh1 * m1 + sh1 * sh1 + EPSF);
  float cc0 = gb[d0] - aa0 * sh0, cc1 = gb[d1] - aa1 * sh1;
  for (int k = 0; k < 65; ++k) {
    float y0 = fmaf(aa0, emb[k * HID + d0], cc0);
    float y1 = fmaf(aa1, emb[k * HID + d1], cc1);
    emb1b[k * (HID / 2) + t] = f2bf(y0) | (f2bf(y1) << 16);
  }
}

// ---------------- chained double-GraphNorm -> per-column affine ----------------
__global__ void k_gnchain(const float* __restrict__ gsum, const float* __restrict__ gsq,
                          float invN, const float* __restrict__ gw, const float* __restrict__ gb,
                          const float* __restrict__ gms, int i1, int i2,
                          float* __restrict__ A, float* __restrict__ C) {
  int d = threadIdx.x;  // 128 threads
  float m = gsum[d] * invN, E2 = gsq[d] * invN;
  float ms1 = gms[i1 * HID + d], w1 = gw[i1 * HID + d], b1 = gb[i1 * HID + d];
  float sh1 = m * ms1;
  float a1 = w1 / sqrtf(E2 - 2.f * sh1 * m + sh1 * sh1 + EPSF);
  float c1 = b1 - a1 * sh1;
  float m2 = a1 * m + c1;
  float E2b = a1 * a1 * E2 + 2.f * a1 * c1 * m + c1 * c1;
  float ms2 = gms[i2 * HID + d], w2 = gw[i2 * HID + d], b2 = gb[i2 * HID + d];
  float sh2 = m2 * ms2;
  float a2 = w2 / sqrtf(E2b - 2.f * sh2 * m2 + sh2 * sh2 + EPSF);
  float c2 = b2 - a2 * sh2;
  A[d] = a2 * a1;
  C[d] = a2 * c1 + c2;
}

// ============ SpMM1: wave-per-node, 2-deep pipelined gathers from bf16 emb1 =========
#define LOADB(B) { _Pragma("unroll") for (int k = 0; k < 8; ++k) B[k] = sedge[p + k]; p += 8; }
#define WCOPY(W, B) { _Pragma("unroll") for (int k = 0; k < 8; ++k) W[k] = __int_as_float(B[k].y); }

__global__ __launch_bounds__(256, 8) void k_spmm1(
    const int* __restrict__ rowptr, const int2* __restrict__ sedge,
    const unsigned* __restrict__ emb1b, int n, int nwaves,
    unsigned* __restrict__ h2b, float* __restrict__ gsum, float* __restrict__ gsq) {
  __shared__ float red[2][4][64][2];
  int t = threadIdx.x;
  int l = t & 63, wv = t >> 6;
  int gwid = blockIdx.x * 4 + wv;
  float ps0 = 0, ps1 = 0, q0s = 0, q1s = 0;

#define GATHER1(U, B) { _Pragma("unroll") for (int k = 0; k < 8; ++k) \
    U[k] = emb1b[(unsigned)(B[k].x >> 17) * (HID / 2) + l]; }
#define COMP1(U, W) { _Pragma("unroll") for (int k = 0; k < 8; ++k) { \
    float w = W[k]; wsum += w; \
    float h0 = __uint_as_float(U[k] << 16); \
    float h1 = __uint_as_float(U[k] & 0xFFFF0000u); \
    a0 = fmaf(w, h0, a0); a1 = fmaf(w, h1, a1); } }

  int p0 = 0, p1 = 0;
  if (gwid < n) { p0 = rowptr[gwid]; p1 = rowptr[gwid + 1]; }
  for (int node = gwid; node < n; node += nwaves) {
    int nxt = node + nwaves;
    int q0 = 0, q1 = 0;
    if (nxt < n) { q0 = rowptr[nxt]; q1 = rowptr[nxt + 1]; }
    int m = p1 - p0;
    int cnt8 = m >> 3;
    int p = p0;
    float wsum = 0.f, a0 = 0.f, a1 = 0.f;
    if (cnt8 >= 2) {
      int2 bA[8], bB[8]; unsigned uA[8], uB[8]; float wA[8], wB[8];
      LOADB(bA); LOADB(bB);
      GATHER1(uA, bA); WCOPY(wA, bA);
      int i = 0;
      for (; i + 3 < cnt8; i += 2) {
        GATHER1(uB, bB); WCOPY(wB, bB);
        LOADB(bA);
        COMP1(uA, wA);
        GATHER1(uA, bA); WCOPY(wA, bA);
        LOADB(bB);
        COMP1(uB, wB);
      }
      if (cnt8 - i == 3) {
        GATHER1(uB, bB); WCOPY(wB, bB);
        LOADB(bA);
        COMP1(uA, wA);
        GATHER1(uA, bA); WCOPY(wA, bA);
        COMP1(uB, wB);
        COMP1(uA, wA);
      } else {
        GATHER1(uB, bB); WCOPY(wB, bB);
        COMP1(uA, wA);
        COMP1(uB, wB);
      }
    } else if (cnt8 == 1) {
      int2 bA[8]; unsigned uA[8]; float wA[8];
      LOADB(bA);
      GATHER1(uA, bA); WCOPY(wA, bA);
      COMP1(uA, wA);
    }
    int r = m & 7;
    if (r) {
      p = p0 + (cnt8 << 3);
      int2 bR[8]; unsigned uR[8];
#pragma unroll
      for (int k = 0; k < 8; ++k) if (k < r) bR[k] = sedge[p + k];
#pragma unroll
      for (int k = 0; k < 8; ++k) if (k < r)
        uR[k] = emb1b[(unsigned)(bR[k].x >> 17) * (HID / 2) + l];
#pragma unroll
      for (int k = 0; k < 8; ++k) if (k < r) {
        float w = __int_as_float(bR[k].y); wsum += w;
        float h0 = __uint_as_float(uR[k] << 16);
        float h1 = __uint_as_float(uR[k] & 0xFFFF0000u);
        a0 = fmaf(w, h0, a0); a1 = fmaf(w, h1, a1);
      }
    }
    float d = (wsum < 0.5f) ? wsum + 1.0f : wsum;
    float invd = 1.0f / d;
    a0 *= invd; a1 *= invd;
    h2b[(size_t)node * (HID / 2) + l] = f2bf(a0) | (f2bf(a1) << 16);
    ps0 += a0; ps1 += a1; q0s += a0 * a0; q1s += a1 * a1;
    p0 = q0; p1 = q1;
  }
  red[0][wv][l][0] = ps0; red[0][wv][l][1] = ps1;
  red[1][wv][l][0] = q0s; red[1][wv][l][1] = q1s;
  __syncthreads();
  if (wv == 0) {
    float s0 = 0, s1 = 0, t0 = 0, t1 = 0;
#pragma unroll
    for (int k = 0; k < 4; ++k) {
      s0 += red[0][k][l][0]; s1 += red[0][k][l][1];
      t0 += red[1][k][l][0]; t1 += red[1][k][l][1];
    }
    atomicAdd(&gsum[l * 2], s0); atomicAdd(&gsum[l * 2 + 1], s1);
    atomicAdd(&gsq[l * 2], t0);  atomicAdd(&gsq[l * 2 + 1], t1);
  }
}

// ============ SpMM2: wave-per-node, 2-deep pipelined bf16 h2 gathers ================
__global__ __launch_bounds__(256, 8) void k_spmm2(
    const int* __restrict__ rowptr, const int2* __restrict__ sedge,
    const unsigned* __restrict__ h2b,
    const float* __restrict__ A, const float* __restrict__ C,
    int n, int nwaves, float* __restrict__ out,
    float* __restrict__ gsum, float* __restrict__ gsq) {
  __shared__ float red[2][4][64][2];
  int t = threadIdx.x;
  int l = t & 63, wv = t >> 6;
  int gwid = blockIdx.x * 4 + wv;
  float A0 = A[l * 2], A1 = A[l * 2 + 1], C0 = C[l * 2], C1 = C[l * 2 + 1];
  float ps0 = 0, ps1 = 0, q0s = 0, q1s = 0;

#define GATHER2(U, B) { _Pragma("unroll") for (int k = 0; k < 8; ++k) \
    U[k] = h2b[(size_t)(B[k].x & 0x1FFFF) * (HID / 2) + l]; }
#define COMP2(U, W) { _Pragma("unroll") for (int k = 0; k < 8; ++k) { \
    float w = W[k]; wsum += w; \
    float h0 = __uint_as_float(U[k] << 16); \
    float h1 = __uint_as_float(U[k] & 0xFFFF0000u); \
    a0 = fmaf(w, fmaxf(fmaf(A0, h0, C0), 0.f), a0); \
    a1 = fmaf(w, fmaxf(fmaf(A1, h1, C1), 0.f), a1); } }

  int p0 = 0, p1 = 0;
  if (gwid < n) { p0 = rowptr[gwid]; p1 = rowptr[gwid + 1]; }
  for (int node = gwid; node < n; node += nwaves) {
    int nxt = node + nwaves;
    int q0 = 0, q1 = 0;
    if (nxt < n) { q0 = rowptr[nxt]; q1 = rowptr[nxt + 1]; }
    int m = p1 - p0;
    int cnt8 = m >> 3;
    int p = p0;
    float wsum = 0.f, a0 = 0.f, a1 = 0.f;
    if (cnt8 >= 2) {
      int2 bA[8], bB[8]; unsigned uA[8], uB[8]; float wA[8], wB[8];
      LOADB(bA); LOADB(bB);
      GATHER2(uA, bA); WCOPY(wA, bA);
      int i = 0;
      for (; i + 3 < cnt8; i += 2) {
        GATHER2(uB, bB); WCOPY(wB, bB);
        LOADB(bA);
        COMP2(uA, wA);
        GATHER2(uA, bA); WCOPY(wA, bA);
        LOADB(bB);
        COMP2(uB, wB);
      }
      if (cnt8 - i == 3) {
        GATHER2(uB, bB); WCOPY(wB, bB);
        LOADB(bA);
        COMP2(uA, wA);
        GATHER2(uA, bA); WCOPY(wA, bA);
        COMP2(uB, wB);
        COMP2(uA, wA);
      } else {
        GATHER2(uB, bB); WCOPY(wB, bB);
        COMP2(uA, wA);
        COMP2(uB, wB);
      }
    } else if (cnt8 == 1) {
      int2 bA[8]; unsigned uA[8]; float wA[8];
      LOADB(bA);
      GATHER2(uA, bA); WCOPY(wA, bA);
      COMP2(uA, wA);
    }
    int r = m & 7;
    if (r) {
      p = p0 + (cnt8 << 3);
      int2 bR[8]; unsigned uR[8];
#pragma unroll
      for (int k = 0; k < 8; ++k) if (k < r) bR[k] = sedge[p + k];
#pragma unroll
      for (int k = 0; k < 8; ++k) if (k < r)
        uR[k] = h2b[(size_t)(bR[k].x & 0x1FFFF) * (HID / 2) + l];
#pragma unroll
      for (int k = 0; k < 8; ++k) if (k < r) {
        float w = __int_as_float(bR[k].y); wsum += w;
        float h0 = __uint_as_float(uR[k] << 16);
        float h1 = __uint_as_float(uR[k] & 0xFFFF0000u);
        a0 = fmaf(w, fmaxf(fmaf(A0, h0, C0), 0.f), a0);
        a1 = fmaf(w, fmaxf(fmaf(A1, h1, C1), 0.f), a1);
      }
    }
    float d = (wsum < 0.5f) ? wsum + 1.0f : wsum;
    float invd = 1.0f / d;
    a0 *= invd; a1 *= invd;
    *(float2*)&out[(size_t)node * HID + l * 2] = make_float2(a0, a1);
    ps0 += a0; ps1 += a1; q0s += a0 * a0; q1s += a1 * a1;
    p0 = q0; p1 = q1;
  }
  red[0][wv][l][0] = ps0; red[0][wv][l][1] = ps1;
  red[1][wv][l][0] = q0s; red[1][wv][l][1] = q1s;
  __syncthreads();
  if (wv == 0) {
    float s0 = 0, s1 = 0, t0 = 0, t1 = 0;
#pragma unroll
    for (int k = 0; k < 4; ++k) {
      s0 += red[0][k][l][0]; s1 += red[0][k][l][1];
      t0 += red[1][k][l][0]; t1 += red[1][k][l][1];
    }
    atomicAdd(&gsum[l * 2], s0); atomicAdd(&gsum[l * 2 + 1], s1);
    atomicAdd(&gsq[l * 2], t0);  atomicAdd(&gsq[l * 2 + 1], t1);
  }
}

// ---------------- final in-place affine on d_out ----------------
__global__ void k_final(float* __restrict__ out, const float* __restrict__ A,
                        const float* __restrict__ C, int n) {
  __shared__ float la[HID], lc[HID];
  if (threadIdx.x < HID) { la[threadIdx.x] = A[threadIdx.x]; lc[threadIdx.x] = C[threadIdx.x]; }
  __syncthreads();
  int total = n * 32;  // float4 count
  for (int i = blockIdx.x * blockDim.x + threadIdx.x; i < total; i += gridDim.x * blockDim.x) {
    float4 v = *(float4*)(out + (size_t)i * 4);
    int cg = (i & 31) * 4;
    v.x = fmaf(la[cg + 0], v.x, lc[cg + 0]);
    v.y = fmaf(la[cg + 1], v.y, lc[cg + 1]);
    v.z = fmaf(la[cg + 2], v.z, lc[cg + 2]);
    v.w = fmaf(la[cg + 3], v.w, lc[cg + 3]);
    *(float4*)(out + (size_t)i * 4) = v;
  }
}

extern "C" void kernel_launch(void* const* d_in, const int* in_sizes, int n_in,
                              void* d_out, int out_size, void* d_ws, size_t ws_size,
                              hipStream_t stream) {
  const int* x = (const int*)d_in[0];
  const int* ei = (const int*)d_in[1];
  const float* ew = (const float*)d_in[2];
  const float* emb = (const float*)d_in[3];
  const float* gw = (const float*)d_in[4];
  const float* gb = (const float*)d_in[5];
  const float* gms = (const float*)d_in[6];
  float* out = (float*)d_out;

  const int n = in_sizes[0];        // 100000
  const int e = in_sizes[1] / 2;    // 1600000
  const int* row = ei;
  const int* col = ei + e;

  // workspace layout, in 4-byte units, 128B-aligned chunks
  float* wsf = (float*)d_ws;
  size_t o = 0;
  auto alloc = [&](size_t elems) -> size_t { size_t r = o; o += ((elems + 31) & ~(size_t)31); return r; };
  size_t cnt_o = alloc(n + 1);
  size_t hist_o = alloc(65);
  size_t sum2_o = alloc(HID), sq2_o = alloc(HID), sum4_o = alloc(HID), sq4_o = alloc(HID);
  size_t zero_end = o;                       // everything above must be zeroed
  size_t A12_o = alloc(HID), C12_o = alloc(HID), A34_o = alloc(HID), C34_o = alloc(HID);
  size_t rowptr_o = alloc(n + 1);
  size_t cursor_o = alloc(n + 1);
  size_t bsum_o = alloc(64);
  size_t emb1b_o = alloc(65 * HID / 2);      // bf16 pairs
  size_t sedge_o = alloc((size_t)e * 2);     // int2 per edge
  size_t h2b_o = alloc((size_t)n * HID / 2); // bf16 pairs (uint) per 2 elements

  int* cnt = (int*)(wsf + cnt_o);
  int* hist = (int*)(wsf + hist_o);
  float* sum2 = wsf + sum2_o; float* sq2 = wsf + sq2_o;
  float* sum4 = wsf + sum4_o; float* sq4 = wsf + sq4_o;
  float* A12 = wsf + A12_o; float* C12 = wsf + C12_o;
  float* A34 = wsf + A34_o; float* C34 = wsf + C34_o;
  int* rowptr = (int*)(wsf + rowptr_o);
  int* cursor = (int*)(wsf + cursor_o);
  int* bsum = (int*)(wsf + bsum_o);
  unsigned* emb1b = (unsigned*)(wsf + emb1b_o);
  int2* sedge = (int2*)(wsf + sedge_o);
  unsigned* h2b = (unsigned*)(wsf + h2b_o);

  const float invN = 1.0f / (float)n;
  const int nblk = 2048;
  const int nwaves = nblk * 4;

  hipMemsetAsync(d_ws, 0, zero_end * sizeof(float), stream);
  k_histcnt<<<2048, 256, 0, stream>>>(x, n, row, e, hist, cnt);
  int nb = (n + 1 + 2047) / 2048;
  k_scan_partial<<<nb, 256, 0, stream>>>(cnt, n + 1, bsum);
  k_scan_bsum<<<1, 64, 0, stream>>>(bsum, nb);
  k_scan_final<<<nb, 256, 0, stream>>>(cnt, n + 1, bsum, rowptr, cursor);
  k_scatter<<<2048, 256, 0, stream>>>(row, col, ew, x, e, cursor, sedge);
  k_gn0<<<1, 64, 0, stream>>>(emb, hist, gw, gb, gms, invN, emb1b);
  k_spmm1<<<nblk, 256, 0, stream>>>(rowptr, sedge, emb1b, n, nwaves, h2b, sum2, sq2);
  k_gnchain<<<1, HID, 0, stream>>>(sum2, sq2, invN, gw, gb, gms, 1, 2, A12, C12);
  k_spmm2<<<nblk, 256, 0, stream>>>(rowptr, sedge, h2b, A12, C12, n, nwaves, out, sum4, sq4);
  k_gnchain<<<1, HID, 0, stream>>>(sum4, sq4, invN, gw, gb, gms, 3, 4, A34, C34);
  k_final<<<2048, 256, 0, stream>>>(out, A34, C34, n);
}

// Round 7
// 597.970 us; speedup vs baseline: 1.7950x; 1.7950x over previous
//
#include <hip/hip_runtime.h>

#define HID 128
#define EPSF 1e-6f

__device__ inline unsigned f2bf(float f) {
  unsigned u = __float_as_uint(f);
  return (u + 0x7fffu + ((u >> 16) & 1u)) >> 16;  // RNE
}

// ---------------- fused histogram of x (65 bins) + per-row edge count ----------------
__global__ void k_histcnt(const int* __restrict__ x, int n, const int* __restrict__ row,
                          int e, int* __restrict__ hist, int* __restrict__ cnt) {
  __shared__ int lh[65];
  int t = threadIdx.x;
  if (t < 65) lh[t] = 0;
  __syncthreads();
  int tid = blockIdx.x * blockDim.x + t, stride = gridDim.x * blockDim.x;
  for (int i = tid; i < e; i += stride) atomicAdd(&cnt[row[i]], 1);
  for (int i = tid; i < n; i += stride) atomicAdd(&lh[x[i]], 1);
  __syncthreads();
  if (t < 65 && lh[t]) atomicAdd(&hist[t], lh[t]);
}

// ---------------- 3-phase exclusive scan over cnt[0..n) -> rowptr ----------------
__global__ void k_scan_partial(const int* __restrict__ cnt, int n, int* __restrict__ bsum) {
  __shared__ int sh[256];
  int t = threadIdx.x;
  int base = blockIdx.x * 2048 + t * 8;
  int s = 0;
#pragma unroll
  for (int j = 0; j < 8; ++j) { int idx = base + j; if (idx < n) s += cnt[idx]; }
  sh[t] = s; __syncthreads();
  for (int off = 128; off > 0; off >>= 1) {
    if (t < off) sh[t] += sh[t + off];
    __syncthreads();
  }
  if (t == 0) bsum[blockIdx.x] = sh[0];
}

__global__ void k_scan_bsum(int* __restrict__ bsum, int nb) {
  if (threadIdx.x == 0 && blockIdx.x == 0) {
    int acc = 0;
    for (int i = 0; i < nb; ++i) { int v = bsum[i]; bsum[i] = acc; acc += v; }
  }
}

__global__ void k_scan_final(const int* __restrict__ cnt, int n, const int* __restrict__ bsum,
                             int* __restrict__ rowptr, int* __restrict__ cursor) {
  __shared__ int sh[256];
  int t = threadIdx.x;
  int base = blockIdx.x * 2048 + t * 8;
  int v[8]; int s = 0;
#pragma unroll
  for (int j = 0; j < 8; ++j) { int idx = base + j; v[j] = (idx < n) ? cnt[idx] : 0; s += v[j]; }
  sh[t] = s; __syncthreads();
  for (int off = 1; off < 256; off <<= 1) {
    int val = (t >= off) ? sh[t - off] : 0;
    __syncthreads();
    sh[t] += val;
    __syncthreads();
  }
  int off0 = bsum[blockIdx.x] + sh[t] - s;  // exclusive prefix for this thread
#pragma unroll
  for (int j = 0; j < 8; ++j) {
    int idx = base + j;
    if (idx < n) { rowptr[idx] = off0; cursor[idx] = off0; off0 += v[j]; }
  }
}

// ---------------- scatter edges into CSR order: ({col | x<<17}, ew), 4-deep MLP ------
__global__ __launch_bounds__(256) void k_scatter(
    const int* __restrict__ row, const int* __restrict__ col,
    const float* __restrict__ ew, const int* __restrict__ x, int e,
    int* __restrict__ cursor, int2* __restrict__ sedge) {
  int tid = blockIdx.x * blockDim.x + threadIdx.x;
  int stride = gridDim.x * blockDim.x;
  for (int i0 = tid; i0 < e; i0 += stride * 4) {
    int r[4], c[4], xc[4], idx[4]; float w[4]; bool valid[4];
#pragma unroll
    for (int k = 0; k < 4; ++k) {
      int i = i0 + k * stride; valid[k] = (i < e);
      if (valid[k]) { r[k] = row[i]; c[k] = col[i]; w[k] = ew[i]; }
    }
#pragma unroll
    for (int k = 0; k < 4; ++k) if (valid[k]) xc[k] = x[c[k]];
#pragma unroll
    for (int k = 0; k < 4; ++k) if (valid[k]) idx[k] = atomicAdd(&cursor[r[k]], 1);
#pragma unroll
    for (int k = 0; k < 4; ++k)
      if (valid[k]) sedge[idx[k]] = make_int2(c[k] | (xc[k] << 17), __float_as_int(w[k]));
  }
}

// ---------------- fold GN0 into bf16-packed embedding table ----------------
__global__ void k_gn0(const float* __restrict__ emb, const int* __restrict__ hist,
                      const float* __restrict__ gw, const float* __restrict__ gb,
                      const float* __restrict__ gms, float invN,
                      unsigned* __restrict__ emb1b) {
  int t = threadIdx.x;  // 64 threads; cols d0=2t, d1=2t+1
  int d0 = t * 2, d1 = t * 2 + 1;
  float s0 = 0, s20 = 0, s1 = 0, s21 = 0;
  for (int k = 0; k < 65; ++k) {
    float c = (float)hist[k];
    float v0 = emb[k * HID + d0], v1 = emb[k * HID + d1];
    s0 += c * v0; s20 += c * v0 * v0;
    s1 += c * v1; s21 += c * v1 * v1;
  }
  float m0 = s0 * invN, E20 = s20 * invN;
  float m1 = s1 * invN, E21 = s21 * invN;
  float sh0 = m0 * gms[d0], sh1 = m1 * gms[d1];
  float aa0 = gw[d0] / sqrtf(E20 - 2.f * sh0 * m0 + sh0 * sh0 + EPSF);
  float aa1 = gw[d1] / sqrtf(E21 - 2.f * sh1 * m1 + sh1 * sh1 + EPSF);
  float cc0 = gb[d0] - aa0 * sh0, cc1 = gb[d1] - aa1 * sh1;
  for (int k = 0; k < 65; ++k) {
    float y0 = fmaf(aa0, emb[k * HID + d0], cc0);
    float y1 = fmaf(aa1, emb[k * HID + d1], cc1);
    emb1b[k * (HID / 2) + t] = f2bf(y0) | (f2bf(y1) << 16);
  }
}

// ---------------- chained double-GraphNorm -> per-column affine ----------------
__global__ void k_gnchain(const float* __restrict__ gsum, const float* __restrict__ gsq,
                          float invN, const float* __restrict__ gw, const float* __restrict__ gb,
                          const float* __restrict__ gms, int i1, int i2,
                          float* __restrict__ A, float* __restrict__ C) {
  int d = threadIdx.x;  // 128 threads
  float m = gsum[d] * invN, E2 = gsq[d] * invN;
  float ms1 = gms[i1 * HID + d], w1 = gw[i1 * HID + d], b1 = gb[i1 * HID + d];
  float sh1 = m * ms1;
  float a1 = w1 / sqrtf(E2 - 2.f * sh1 * m + sh1 * sh1 + EPSF);
  float c1 = b1 - a1 * sh1;
  float m2 = a1 * m + c1;
  float E2b = a1 * a1 * E2 + 2.f * a1 * c1 * m + c1 * c1;
  float ms2 = gms[i2 * HID + d], w2 = gw[i2 * HID + d], b2 = gb[i2 * HID + d];
  float sh2 = m2 * ms2;
  float a2 = w2 / sqrtf(E2b - 2.f * sh2 * m2 + sh2 * sh2 + EPSF);
  float c2 = b2 - a2 * sh2;
  A[d] = a2 * a1;
  C[d] = a2 * c1 + c2;
}

// ============ SpMM1: wave-per-node, 2-deep pipelined gathers from bf16 emb1 =========
#define LOADB(B) { _Pragma("unroll") for (int k = 0; k < 8; ++k) B[k] = sedge[p + k]; p += 8; }
#define WCOPY(W, B) { _Pragma("unroll") for (int k = 0; k < 8; ++k) W[k] = __int_as_float(B[k].y); }

__global__ __launch_bounds__(256) void k_spmm1(
    const int* __restrict__ rowptr, const int2* __restrict__ sedge,
    const unsigned* __restrict__ emb1b, int n, int nwaves,
    unsigned* __restrict__ h2b, float* __restrict__ gsum, float* __restrict__ gsq) {
  __shared__ float red[2][4][64][2];
  int t = threadIdx.x;
  int l = t & 63, wv = t >> 6;
  int gwid = blockIdx.x * 4 + wv;
  float ps0 = 0, ps1 = 0, q0s = 0, q1s = 0;

#define GATHER1(U, B) { _Pragma("unroll") for (int k = 0; k < 8; ++k) \
    U[k] = emb1b[(unsigned)(B[k].x >> 17) * (HID / 2) + l]; }
#define COMP1(U, W) { _Pragma("unroll") for (int k = 0; k < 8; ++k) { \
    float w = W[k]; wsum += w; \
    float h0 = __uint_as_float(U[k] << 16); \
    float h1 = __uint_as_float(U[k] & 0xFFFF0000u); \
    a0 = fmaf(w, h0, a0); a1 = fmaf(w, h1, a1); } }

  int p0 = 0, p1 = 0;
  if (gwid < n) { p0 = rowptr[gwid]; p1 = rowptr[gwid + 1]; }
  for (int node = gwid; node < n; node += nwaves) {
    int nxt = node + nwaves;
    int q0 = 0, q1 = 0;
    if (nxt < n) { q0 = rowptr[nxt]; q1 = rowptr[nxt + 1]; }
    int m = p1 - p0;
    int cnt8 = m >> 3;
    int p = p0;
    float wsum = 0.f, a0 = 0.f, a1 = 0.f;
    if (cnt8 >= 2) {
      int2 bA[8], bB[8]; unsigned uA[8], uB[8]; float wA[8], wB[8];
      LOADB(bA); LOADB(bB);
      GATHER1(uA, bA); WCOPY(wA, bA);
      int i = 0;
      for (; i + 3 < cnt8; i += 2) {
        GATHER1(uB, bB); WCOPY(wB, bB);
        LOADB(bA);
        COMP1(uA, wA);
        GATHER1(uA, bA); WCOPY(wA, bA);
        LOADB(bB);
        COMP1(uB, wB);
      }
      if (cnt8 - i == 3) {
        GATHER1(uB, bB); WCOPY(wB, bB);
        LOADB(bA);
        COMP1(uA, wA);
        GATHER1(uA, bA); WCOPY(wA, bA);
        COMP1(uB, wB);
        COMP1(uA, wA);
      } else {
        GATHER1(uB, bB); WCOPY(wB, bB);
        COMP1(uA, wA);
        COMP1(uB, wB);
      }
    } else if (cnt8 == 1) {
      int2 bA[8]; unsigned uA[8]; float wA[8];
      LOADB(bA);
      GATHER1(uA, bA); WCOPY(wA, bA);
      COMP1(uA, wA);
    }
    int r = m & 7;
    if (r) {
      p = p0 + (cnt8 << 3);
      int2 bR[8]; unsigned uR[8];
#pragma unroll
      for (int k = 0; k < 8; ++k) if (k < r) bR[k] = sedge[p + k];
#pragma unroll
      for (int k = 0; k < 8; ++k) if (k < r)
        uR[k] = emb1b[(unsigned)(bR[k].x >> 17) * (HID / 2) + l];
#pragma unroll
      for (int k = 0; k < 8; ++k) if (k < r) {
        float w = __int_as_float(bR[k].y); wsum += w;
        float h0 = __uint_as_float(uR[k] << 16);
        float h1 = __uint_as_float(uR[k] & 0xFFFF0000u);
        a0 = fmaf(w, h0, a0); a1 = fmaf(w, h1, a1);
      }
    }
    float d = (wsum < 0.5f) ? wsum + 1.0f : wsum;
    float invd = 1.0f / d;
    a0 *= invd; a1 *= invd;
    h2b[(size_t)node * (HID / 2) + l] = f2bf(a0) | (f2bf(a1) << 16);
    ps0 += a0; ps1 += a1; q0s += a0 * a0; q1s += a1 * a1;
    p0 = q0; p1 = q1;
  }
  red[0][wv][l][0] = ps0; red[0][wv][l][1] = ps1;
  red[1][wv][l][0] = q0s; red[1][wv][l][1] = q1s;
  __syncthreads();
  if (wv == 0) {
    float s0 = 0, s1 = 0, t0 = 0, t1 = 0;
#pragma unroll
    for (int k = 0; k < 4; ++k) {
      s0 += red[0][k][l][0]; s1 += red[0][k][l][1];
      t0 += red[1][k][l][0]; t1 += red[1][k][l][1];
    }
    atomicAdd(&gsum[l * 2], s0); atomicAdd(&gsum[l * 2 + 1], s1);
    atomicAdd(&gsq[l * 2], t0);  atomicAdd(&gsq[l * 2 + 1], t1);
  }
}

// ============ SpMM2: wave-per-node, 2-deep pipelined bf16 h2 gathers ================
__global__ __launch_bounds__(256) void k_spmm2(
    const int* __restrict__ rowptr, const int2* __restrict__ sedge,
    const unsigned* __restrict__ h2b,
    const float* __restrict__ A, const float* __restrict__ C,
    int n, int nwaves, float* __restrict__ out,
    float* __restrict__ gsum, float* __restrict__ gsq) {
  __shared__ float red[2][4][64][2];
  int t = threadIdx.x;
  int l = t & 63, wv = t >> 6;
  int gwid = blockIdx.x * 4 + wv;
  float A0 = A[l * 2], A1 = A[l * 2 + 1], C0 = C[l * 2], C1 = C[l * 2 + 1];
  float ps0 = 0, ps1 = 0, q0s = 0, q1s = 0;

#define GATHER2(U, B) { _Pragma("unroll") for (int k = 0; k < 8; ++k) \
    U[k] = h2b[(size_t)(B[k].x & 0x1FFFF) * (HID / 2) + l]; }
#define COMP2(U, W) { _Pragma("unroll") for (int k = 0; k < 8; ++k) { \
    float w = W[k]; wsum += w; \
    float h0 = __uint_as_float(U[k] << 16); \
    float h1 = __uint_as_float(U[k] & 0xFFFF0000u); \
    a0 = fmaf(w, fmaxf(fmaf(A0, h0, C0), 0.f), a0); \
    a1 = fmaf(w, fmaxf(fmaf(A1, h1, C1), 0.f), a1); } }

  int p0 = 0, p1 = 0;
  if (gwid < n) { p0 = rowptr[gwid]; p1 = rowptr[gwid + 1]; }
  for (int node = gwid; node < n; node += nwaves) {
    int nxt = node + nwaves;
    int q0 = 0, q1 = 0;
    if (nxt < n) { q0 = rowptr[nxt]; q1 = rowptr[nxt + 1]; }
    int m = p1 - p0;
    int cnt8 = m >> 3;
    int p = p0;
    float wsum = 0.f, a0 = 0.f, a1 = 0.f;
    if (cnt8 >= 2) {
      int2 bA[8], bB[8]; unsigned uA[8], uB[8]; float wA[8], wB[8];
      LOADB(bA); LOADB(bB);
      GATHER2(uA, bA); WCOPY(wA, bA);
      int i = 0;
      for (; i + 3 < cnt8; i += 2) {
        GATHER2(uB, bB); WCOPY(wB, bB);
        LOADB(bA);
        COMP2(uA, wA);
        GATHER2(uA, bA); WCOPY(wA, bA);
        LOADB(bB);
        COMP2(uB, wB);
      }
      if (cnt8 - i == 3) {
        GATHER2(uB, bB); WCOPY(wB, bB);
        LOADB(bA);
        COMP2(uA, wA);
        GATHER2(uA, bA); WCOPY(wA, bA);
        COMP2(uB, wB);
        COMP2(uA, wA);
      } else {
        GATHER2(uB, bB); WCOPY(wB, bB);
        COMP2(uA, wA);
        COMP2(uB, wB);
      }
    } else if (cnt8 == 1) {
      int2 bA[8]; unsigned uA[8]; float wA[8];
      LOADB(bA);
      GATHER2(uA, bA); WCOPY(wA, bA);
      COMP2(uA, wA);
    }
    int r = m & 7;
    if (r) {
      p = p0 + (cnt8 << 3);
      int2 bR[8]; unsigned uR[8];
#pragma unroll
      for (int k = 0; k < 8; ++k) if (k < r) bR[k] = sedge[p + k];
#pragma unroll
      for (int k = 0; k < 8; ++k) if (k < r)
        uR[k] = h2b[(size_t)(bR[k].x & 0x1FFFF) * (HID / 2) + l];
#pragma unroll
      for (int k = 0; k < 8; ++k) if (k < r) {
        float w = __int_as_float(bR[k].y); wsum += w;
        float h0 = __uint_as_float(uR[k] << 16);
        float h1 = __uint_as_float(uR[k] & 0xFFFF0000u);
        a0 = fmaf(w, fmaxf(fmaf(A0, h0, C0), 0.f), a0);
        a1 = fmaf(w, fmaxf(fmaf(A1, h1, C1), 0.f), a1);
      }
    }
    float d = (wsum < 0.5f) ? wsum + 1.0f : wsum;
    float invd = 1.0f / d;
    a0 *= invd; a1 *= invd;
    *(float2*)&out[(size_t)node * HID + l * 2] = make_float2(a0, a1);
    ps0 += a0; ps1 += a1; q0s += a0 * a0; q1s += a1 * a1;
    p0 = q0; p1 = q1;
  }
  red[0][wv][l][0] = ps0; red[0][wv][l][1] = ps1;
  red[1][wv][l][0] = q0s; red[1][wv][l][1] = q1s;
  __syncthreads();
  if (wv == 0) {
    float s0 = 0, s1 = 0, t0 = 0, t1 = 0;
#pragma unroll
    for (int k = 0; k < 4; ++k) {
      s0 += red[0][k][l][0]; s1 += red[0][k][l][1];
      t0 += red[1][k][l][0]; t1 += red[1][k][l][1];
    }
    atomicAdd(&gsum[l * 2], s0); atomicAdd(&gsum[l * 2 + 1], s1);
    atomicAdd(&gsq[l * 2], t0);  atomicAdd(&gsq[l * 2 + 1], t1);
  }
}

// ---------------- final in-place affine on d_out ----------------
__global__ void k_final(float* __restrict__ out, const float* __restrict__ A,
                        const float* __restrict__ C, int n) {
  __shared__ float la[HID], lc[HID];
  if (threadIdx.x < HID) { la[threadIdx.x] = A[threadIdx.x]; lc[threadIdx.x] = C[threadIdx.x]; }
  __syncthreads();
  int total = n * 32;  // float4 count
  for (int i = blockIdx.x * blockDim.x + threadIdx.x; i < total; i += gridDim.x * blockDim.x) {
    float4 v = *(float4*)(out + (size_t)i * 4);
    int cg = (i & 31) * 4;
    v.x = fmaf(la[cg + 0], v.x, lc[cg + 0]);
    v.y = fmaf(la[cg + 1], v.y, lc[cg + 1]);
    v.z = fmaf(la[cg + 2], v.z, lc[cg + 2]);
    v.w = fmaf(la[cg + 3], v.w, lc[cg + 3]);
    *(float4*)(out + (size_t)i * 4) = v;
  }
}

extern "C" void kernel_launch(void* const* d_in, const int* in_sizes, int n_in,
                              void* d_out, int out_size, void* d_ws, size_t ws_size,
                              hipStream_t stream) {
  const int* x = (const int*)d_in[0];
  const int* ei = (const int*)d_in[1];
  const float* ew = (const float*)d_in[2];
  const float* emb = (const float*)d_in[3];
  const float* gw = (const float*)d_in[4];
  const float* gb = (const float*)d_in[5];
  const float* gms = (const float*)d_in[6];
  float* out = (float*)d_out;

  const int n = in_sizes[0];        // 100000
  const int e = in_sizes[1] / 2;    // 1600000
  const int* row = ei;
  const int* col = ei + e;

  // workspace layout, in 4-byte units, 128B-aligned chunks
  float* wsf = (float*)d_ws;
  size_t o = 0;
  auto alloc = [&](size_t elems) -> size_t { size_t r = o; o += ((elems + 31) & ~(size_t)31); return r; };
  size_t cnt_o = alloc(n + 1);
  size_t hist_o = alloc(65);
  size_t sum2_o = alloc(HID), sq2_o = alloc(HID), sum4_o = alloc(HID), sq4_o = alloc(HID);
  size_t zero_end = o;                       // everything above must be zeroed
  size_t A12_o = alloc(HID), C12_o = alloc(HID), A34_o = alloc(HID), C34_o = alloc(HID);
  size_t rowptr_o = alloc(n + 1);
  size_t cursor_o = alloc(n + 1);
  size_t bsum_o = alloc(64);
  size_t emb1b_o = alloc(65 * HID / 2);      // bf16 pairs
  size_t sedge_o = alloc((size_t)e * 2);     // int2 per edge
  size_t h2b_o = alloc((size_t)n * HID / 2); // bf16 pairs (uint) per 2 elements

  int* cnt = (int*)(wsf + cnt_o);
  int* hist = (int*)(wsf + hist_o);
  float* sum2 = wsf + sum2_o; float* sq2 = wsf + sq2_o;
  float* sum4 = wsf + sum4_o; float* sq4 = wsf + sq4_o;
  float* A12 = wsf + A12_o; float* C12 = wsf + C12_o;
  float* A34 = wsf + A34_o; float* C34 = wsf + C34_o;
  int* rowptr = (int*)(wsf + rowptr_o);
  int* cursor = (int*)(wsf + cursor_o);
  int* bsum = (int*)(wsf + bsum_o);
  unsigned* emb1b = (unsigned*)(wsf + emb1b_o);
  int2* sedge = (int2*)(wsf + sedge_o);
  unsigned* h2b = (unsigned*)(wsf + h2b_o);

  const float invN = 1.0f / (float)n;
  const int nblk = 2048;
  const int nwaves = nblk * 4;

  hipMemsetAsync(d_ws, 0, zero_end * sizeof(float), stream);
  k_histcnt<<<2048, 256, 0, stream>>>(x, n, row, e, hist, cnt);
  int nb = (n + 1 + 2047) / 2048;
  k_scan_partial<<<nb, 256, 0, stream>>>(cnt, n + 1, bsum);
  k_scan_bsum<<<1, 64, 0, stream>>>(bsum, nb);
  k_scan_final<<<nb, 256, 0, stream>>>(cnt, n + 1, bsum, rowptr, cursor);
  k_scatter<<<2048, 256, 0, stream>>>(row, col, ew, x, e, cursor, sedge);
  k_gn0<<<1, 64, 0, stream>>>(emb, hist, gw, gb, gms, invN, emb1b);
  k_spmm1<<<nblk, 256, 0, stream>>>(rowptr, sedge, emb1b, n, nwaves, h2b, sum2, sq2);
  k_gnchain<<<1, HID, 0, stream>>>(sum2, sq2, invN, gw, gb, gms, 1, 2, A12, C12);
  k_spmm2<<<nblk, 256, 0, stream>>>(rowptr, sedge, h2b, A12, C12, n, nwaves, out, sum4, sq4);
  k_gnchain<<<1, HID, 0, stream>>>(sum4, sq4, invN, gw, gb, gms, 3, 4, A34, C34);
  k_final<<<2048, 256, 0, stream>>>(out, A34, C34, n);
}

// Round 8
// 587.332 us; speedup vs baseline: 1.8275x; 1.0181x over previous
//
#include <hip/hip_runtime.h>

#define HID 128
#define EPSF 1e-6f

__device__ inline unsigned f2bf(float f) {
  unsigned u = __float_as_uint(f);
  return (u + 0x7fffu + ((u >> 16) & 1u)) >> 16;  // RNE
}
__device__ inline float bf2f_lo(unsigned u) { return __uint_as_float(u << 16); }
__device__ inline float bf2f_hi(unsigned u) { return __uint_as_float(u & 0xFFFF0000u); }

// ---------------- fused histogram of x (65 bins) + per-row edge count ----------------
__global__ void k_histcnt(const int* __restrict__ x, int n, const int* __restrict__ row,
                          int e, int* __restrict__ hist, int* __restrict__ cnt) {
  __shared__ int lh[65];
  int t = threadIdx.x;
  if (t < 65) lh[t] = 0;
  __syncthreads();
  int tid = blockIdx.x * blockDim.x + t, stride = gridDim.x * blockDim.x;
  for (int i = tid; i < e; i += stride) atomicAdd(&cnt[row[i]], 1);
  for (int i = tid; i < n; i += stride) atomicAdd(&lh[x[i]], 1);
  __syncthreads();
  if (t < 65 && lh[t]) atomicAdd(&hist[t], lh[t]);
}

// ---------------- 3-phase exclusive scan over cnt[0..n) -> rowptr ----------------
__global__ void k_scan_partial(const int* __restrict__ cnt, int n, int* __restrict__ bsum) {
  __shared__ int sh[256];
  int t = threadIdx.x;
  int base = blockIdx.x * 2048 + t * 8;
  int s = 0;
#pragma unroll
  for (int j = 0; j < 8; ++j) { int idx = base + j; if (idx < n) s += cnt[idx]; }
  sh[t] = s; __syncthreads();
  for (int off = 128; off > 0; off >>= 1) {
    if (t < off) sh[t] += sh[t + off];
    __syncthreads();
  }
  if (t == 0) bsum[blockIdx.x] = sh[0];
}

__global__ void k_scan_bsum(int* __restrict__ bsum, int nb) {
  if (threadIdx.x == 0 && blockIdx.x == 0) {
    int acc = 0;
    for (int i = 0; i < nb; ++i) { int v = bsum[i]; bsum[i] = acc; acc += v; }
  }
}

__global__ void k_scan_final(const int* __restrict__ cnt, int n, const int* __restrict__ bsum,
                             int* __restrict__ rowptr, int* __restrict__ cursor) {
  __shared__ int sh[256];
  int t = threadIdx.x;
  int base = blockIdx.x * 2048 + t * 8;
  int v[8]; int s = 0;
#pragma unroll
  for (int j = 0; j < 8; ++j) { int idx = base + j; v[j] = (idx < n) ? cnt[idx] : 0; s += v[j]; }
  sh[t] = s; __syncthreads();
  for (int off = 1; off < 256; off <<= 1) {
    int val = (t >= off) ? sh[t - off] : 0;
    __syncthreads();
    sh[t] += val;
    __syncthreads();
  }
  int off0 = bsum[blockIdx.x] + sh[t] - s;  // exclusive prefix for this thread
#pragma unroll
  for (int j = 0; j < 8; ++j) {
    int idx = base + j;
    if (idx < n) { rowptr[idx] = off0; cursor[idx] = off0; off0 += v[j]; }
  }
}

// ---------------- scatter edges into CSR order: ({col | x<<17}, ew), 4-deep MLP ------
__global__ __launch_bounds__(256) void k_scatter(
    const int* __restrict__ row, const int* __restrict__ col,
    const float* __restrict__ ew, const int* __restrict__ x, int e,
    int* __restrict__ cursor, int2* __restrict__ sedge) {
  int tid = blockIdx.x * blockDim.x + threadIdx.x;
  int stride = gridDim.x * blockDim.x;
  for (int i0 = tid; i0 < e; i0 += stride * 4) {
    int r[4], c[4], xc[4], idx[4]; float w[4]; bool valid[4];
#pragma unroll
    for (int k = 0; k < 4; ++k) {
      int i = i0 + k * stride; valid[k] = (i < e);
      if (valid[k]) { r[k] = row[i]; c[k] = col[i]; w[k] = ew[i]; }
    }
#pragma unroll
    for (int k = 0; k < 4; ++k) if (valid[k]) xc[k] = x[c[k]];
#pragma unroll
    for (int k = 0; k < 4; ++k) if (valid[k]) idx[k] = atomicAdd(&cursor[r[k]], 1);
#pragma unroll
    for (int k = 0; k < 4; ++k)
      if (valid[k]) sedge[idx[k]] = make_int2(c[k] | (xc[k] << 17), __float_as_int(w[k]));
  }
}

// ---------------- fold GN0 into bf16-packed embedding table ----------------
__global__ void k_gn0(const float* __restrict__ emb, const int* __restrict__ hist,
                      const float* __restrict__ gw, const float* __restrict__ gb,
                      const float* __restrict__ gms, float invN,
                      unsigned* __restrict__ emb1b) {
  int t = threadIdx.x;  // 64 threads; cols d0=2t, d1=2t+1
  int d0 = t * 2, d1 = t * 2 + 1;
  float s0 = 0, s20 = 0, s1 = 0, s21 = 0;
  for (int k = 0; k < 65; ++k) {
    float c = (float)hist[k];
    float v0 = emb[k * HID + d0], v1 = emb[k * HID + d1];
    s0 += c * v0; s20 += c * v0 * v0;
    s1 += c * v1; s21 += c * v1 * v1;
  }
  float m0 = s0 * invN, E20 = s20 * invN;
  float m1 = s1 * invN, E21 = s21 * invN;
  float sh0 = m0 * gms[d0], sh1 = m1 * gms[d1];
  float aa0 = gw[d0] / sqrtf(E20 - 2.f * sh0 * m0 + sh0 * sh0 + EPSF);
  float aa1 = gw[d1] / sqrtf(E21 - 2.f * sh1 * m1 + sh1 * sh1 + EPSF);
  float cc0 = gb[d0] - aa0 * sh0, cc1 = gb[d1] - aa1 * sh1;
  for (int k = 0; k < 65; ++k) {
    float y0 = fmaf(aa0, emb[k * HID + d0], cc0);
    float y1 = fmaf(aa1, emb[k * HID + d1], cc1);
    emb1b[k * (HID / 2) + t] = f2bf(y0) | (f2bf(y1) << 16);
  }
}

// ---- chained double-GraphNorm -> affine; optionally fold int8 dequant scale --------
__global__ void k_gnchain(const float* __restrict__ gsum, const float* __restrict__ gsq,
                          float invN, const float* __restrict__ gw, const float* __restrict__ gb,
                          const float* __restrict__ gms, int i1, int i2,
                          float* __restrict__ A, float* __restrict__ C,
                          const float* __restrict__ hmax, float* __restrict__ Aq,
                          float* __restrict__ qinv) {
  int d = threadIdx.x;  // 128 threads
  float m = gsum[d] * invN, E2 = gsq[d] * invN;
  float ms1 = gms[i1 * HID + d], w1 = gw[i1 * HID + d], b1 = gb[i1 * HID + d];
  float sh1 = m * ms1;
  float a1 = w1 / sqrtf(E2 - 2.f * sh1 * m + sh1 * sh1 + EPSF);
  float c1 = b1 - a1 * sh1;
  float m2 = a1 * m + c1;
  float E2b = a1 * a1 * E2 + 2.f * a1 * c1 * m + c1 * c1;
  float ms2 = gms[i2 * HID + d], w2 = gw[i2 * HID + d], b2 = gb[i2 * HID + d];
  float sh2 = m2 * ms2;
  float a2 = w2 / sqrtf(E2b - 2.f * sh2 * m2 + sh2 * sh2 + EPSF);
  float c2 = b2 - a2 * sh2;
  float Af = a2 * a1, Cf = a2 * c1 + c2;
  A[d] = Af; C[d] = Cf;
  if (hmax) {
    float h = hmax[d];                       // max |h2| per column (bf16-rounded domain)
    Aq[d] = Af * (h * (1.0f / 127.0f));      // dequant folded into affine
    qinv[d] = (h > 0.f) ? 127.0f / h : 0.f;
  }
}

// ============ SpMM1: wave-per-node, bf16 LDS table (16.6 KB), fused hmax ============
__global__ __launch_bounds__(256) void k_spmm1(
    const int* __restrict__ rowptr, const int2* __restrict__ sedge,
    const unsigned* __restrict__ emb1b, int n, int nwaves,
    unsigned* __restrict__ h2b, float* __restrict__ gsum, float* __restrict__ gsq,
    unsigned* __restrict__ hmax) {
  __shared__ unsigned lemb[65 * 64];
  __shared__ float red[2][4][64][2];
  __shared__ float rmx[4][64][2];
  int t = threadIdx.x;
  for (int i = t; i < 65 * 64; i += 256) lemb[i] = emb1b[i];
  __syncthreads();
  int l = t & 63, wv = t >> 6;
  int gwid = blockIdx.x * 4 + wv;
  float ps0 = 0, ps1 = 0, q0s = 0, q1s = 0, m0 = 0, m1 = 0;
  for (int node = gwid; node < n; node += nwaves) {
    int nd = __builtin_amdgcn_readfirstlane(node);
    int p0 = rowptr[nd], p1 = rowptr[nd + 1];
    float wsum = 0.f, a0 = 0.f, a1 = 0.f;
    int p = p0;
    int nfull = p0 + ((p1 - p0) & ~7);
    for (; p < nfull; p += 8) {
      int2 b[8];
#pragma unroll
      for (int k = 0; k < 8; ++k) b[k] = sedge[p + k];
#pragma unroll
      for (int k = 0; k < 8; ++k) {
        unsigned v = lemb[(unsigned)(b[k].x >> 17) * 64 + l];
        float w = __int_as_float(b[k].y);
        wsum += w;
        a0 = fmaf(w, bf2f_lo(v), a0);
        a1 = fmaf(w, bf2f_hi(v), a1);
      }
    }
    for (; p < p1; ++p) {
      int2 b = sedge[p];
      unsigned v = lemb[(unsigned)(b.x >> 17) * 64 + l];
      float w = __int_as_float(b.y);
      wsum += w;
      a0 = fmaf(w, bf2f_lo(v), a0);
      a1 = fmaf(w, bf2f_hi(v), a1);
    }
    float d = (wsum < 0.5f) ? wsum + 1.0f : wsum;
    float invd = 1.0f / d;
    a0 *= invd; a1 *= invd;
    unsigned b0 = f2bf(a0), b1 = f2bf(a1);
    h2b[(size_t)node * 64 + l] = b0 | (b1 << 16);
    m0 = fmaxf(m0, fabsf(__uint_as_float(b0 << 16)));  // max over the STORED (rounded) values
    m1 = fmaxf(m1, fabsf(__uint_as_float(b1 << 16)));
    ps0 += a0; ps1 += a1; q0s += a0 * a0; q1s += a1 * a1;
  }
  red[0][wv][l][0] = ps0; red[0][wv][l][1] = ps1;
  red[1][wv][l][0] = q0s; red[1][wv][l][1] = q1s;
  rmx[wv][l][0] = m0; rmx[wv][l][1] = m1;
  __syncthreads();
  if (wv == 0) {
    float s0 = 0, s1 = 0, t0 = 0, t1 = 0, x0 = 0, x1 = 0;
#pragma unroll
    for (int k = 0; k < 4; ++k) {
      s0 += red[0][k][l][0]; s1 += red[0][k][l][1];
      t0 += red[1][k][l][0]; t1 += red[1][k][l][1];
      x0 = fmaxf(x0, rmx[k][l][0]); x1 = fmaxf(x1, rmx[k][l][1]);
    }
    atomicAdd(&gsum[l * 2], s0); atomicAdd(&gsum[l * 2 + 1], s1);
    atomicAdd(&gsq[l * 2], t0);  atomicAdd(&gsq[l * 2 + 1], t1);
    atomicMax(&hmax[l * 2], __float_as_uint(x0));       // positive floats order as uints
    atomicMax(&hmax[l * 2 + 1], __float_as_uint(x1));
  }
}

// ---------------- quantize h2 (bf16) -> int8 per-column scale ----------------
__global__ __launch_bounds__(256) void k_quant(const unsigned* __restrict__ h2b,
                                               const float* __restrict__ qinv, int n,
                                               unsigned* __restrict__ qmat) {
  int stride = gridDim.x * blockDim.x;
  int total = n * 32;  // 4-col groups
  for (int idx = blockIdx.x * blockDim.x + threadIdx.x; idx < total; idx += stride) {
    int node = idx >> 5, g = idx & 31;
    const unsigned* src = &h2b[(size_t)node * 64 + g * 2];
    unsigned v0 = src[0], v1 = src[1];
    float4 qv = *(const float4*)&qinv[g * 4];
    int c0 = (int)rintf(bf2f_lo(v0) * qv.x);
    int c1 = (int)rintf(bf2f_hi(v0) * qv.y);
    int c2 = (int)rintf(bf2f_lo(v1) * qv.z);
    int c3 = (int)rintf(bf2f_hi(v1) * qv.w);
    qmat[idx] = (unsigned)(c0 & 0xFF) | ((unsigned)(c1 & 0xFF) << 8) |
                ((unsigned)(c2 & 0xFF) << 16) | ((unsigned)(c3 & 0xFF) << 24);
  }
}

// ============ SpMM2: wave-per-node, int8 gathers (128 B/row = 2 lines) ==============
__global__ __launch_bounds__(256) void k_spmm2(
    const int* __restrict__ rowptr, const int2* __restrict__ sedge,
    const unsigned char* __restrict__ qmat,
    const float* __restrict__ Aq, const float* __restrict__ C,
    int n, int nwaves, float* __restrict__ out,
    float* __restrict__ gsum, float* __restrict__ gsq) {
  __shared__ float red[2][4][64][2];
  int t = threadIdx.x;
  int l = t & 63, wv = t >> 6;
  int gwid = blockIdx.x * 4 + wv;
  float A0 = Aq[l * 2], A1 = Aq[l * 2 + 1], C0 = C[l * 2], C1 = C[l * 2 + 1];
  float ps0 = 0, ps1 = 0, q0s = 0, q1s = 0;
  for (int node = gwid; node < n; node += nwaves) {
    int nd = __builtin_amdgcn_readfirstlane(node);
    int p0 = rowptr[nd], p1 = rowptr[nd + 1];
    float wsum = 0.f, a0 = 0.f, a1 = 0.f;
    int p = p0;
    int nfull = p0 + ((p1 - p0) & ~7);
    for (; p < nfull; p += 8) {
      int2 b[8];
#pragma unroll
      for (int k = 0; k < 8; ++k) b[k] = sedge[p + k];
      unsigned short u[8];
#pragma unroll
      for (int k = 0; k < 8; ++k)
        u[k] = *(const unsigned short*)&qmat[(size_t)(b[k].x & 0x1FFFF) * 128 + l * 2];
#pragma unroll
      for (int k = 0; k < 8; ++k) {
        float w = __int_as_float(b[k].y);
        wsum += w;
        float y0 = fmaxf(fmaf(A0, (float)(signed char)(u[k] & 0xFF), C0), 0.f);
        float y1 = fmaxf(fmaf(A1, (float)(signed char)(u[k] >> 8), C1), 0.f);
        a0 = fmaf(w, y0, a0);
        a1 = fmaf(w, y1, a1);
      }
    }
    for (; p < p1; ++p) {
      int2 b = sedge[p];
      unsigned short u = *(const unsigned short*)&qmat[(size_t)(b.x & 0x1FFFF) * 128 + l * 2];
      float w = __int_as_float(b.y);
      wsum += w;
      float y0 = fmaxf(fmaf(A0, (float)(signed char)(u & 0xFF), C0), 0.f);
      float y1 = fmaxf(fmaf(A1, (float)(signed char)(u >> 8), C1), 0.f);
      a0 = fmaf(w, y0, a0);
      a1 = fmaf(w, y1, a1);
    }
    float d = (wsum < 0.5f) ? wsum + 1.0f : wsum;
    float invd = 1.0f / d;
    a0 *= invd; a1 *= invd;
    *(float2*)&out[(size_t)node * HID + l * 2] = make_float2(a0, a1);
    ps0 += a0; ps1 += a1; q0s += a0 * a0; q1s += a1 * a1;
  }
  red[0][wv][l][0] = ps0; red[0][wv][l][1] = ps1;
  red[1][wv][l][0] = q0s; red[1][wv][l][1] = q1s;
  __syncthreads();
  if (wv == 0) {
    float s0 = 0, s1 = 0, t0 = 0, t1 = 0;
#pragma unroll
    for (int k = 0; k < 4; ++k) {
      s0 += red[0][k][l][0]; s1 += red[0][k][l][1];
      t0 += red[1][k][l][0]; t1 += red[1][k][l][1];
    }
    atomicAdd(&gsum[l * 2], s0); atomicAdd(&gsum[l * 2 + 1], s1);
    atomicAdd(&gsq[l * 2], t0);  atomicAdd(&gsq[l * 2 + 1], t1);
  }
}

// ---------------- final in-place affine on d_out ----------------
__global__ void k_final(float* __restrict__ out, const float* __restrict__ A,
                        const float* __restrict__ C, int n) {
  __shared__ float la[HID], lc[HID];
  if (threadIdx.x < HID) { la[threadIdx.x] = A[threadIdx.x]; lc[threadIdx.x] = C[threadIdx.x]; }
  __syncthreads();
  int total = n * 32;  // float4 count
  for (int i = blockIdx.x * blockDim.x + threadIdx.x; i < total; i += gridDim.x * blockDim.x) {
    float4 v = *(float4*)(out + (size_t)i * 4);
    int cg = (i & 31) * 4;
    v.x = fmaf(la[cg + 0], v.x, lc[cg + 0]);
    v.y = fmaf(la[cg + 1], v.y, lc[cg + 1]);
    v.z = fmaf(la[cg + 2], v.z, lc[cg + 2]);
    v.w = fmaf(la[cg + 3], v.w, lc[cg + 3]);
    *(float4*)(out + (size_t)i * 4) = v;
  }
}

extern "C" void kernel_launch(void* const* d_in, const int* in_sizes, int n_in,
                              void* d_out, int out_size, void* d_ws, size_t ws_size,
                              hipStream_t stream) {
  const int* x = (const int*)d_in[0];
  const int* ei = (const int*)d_in[1];
  const float* ew = (const float*)d_in[2];
  const float* emb = (const float*)d_in[3];
  const float* gw = (const float*)d_in[4];
  const float* gb = (const float*)d_in[5];
  const float* gms = (const float*)d_in[6];
  float* out = (float*)d_out;

  const int n = in_sizes[0];        // 100000
  const int e = in_sizes[1] / 2;    // 1600000
  const int* row = ei;
  const int* col = ei + e;

  // workspace layout, in 4-byte units, 128B-aligned chunks
  float* wsf = (float*)d_ws;
  size_t o = 0;
  auto alloc = [&](size_t elems) -> size_t { size_t r = o; o += ((elems + 31) & ~(size_t)31); return r; };
  size_t cnt_o = alloc(n + 1);
  size_t hist_o = alloc(65);
  size_t sum2_o = alloc(HID), sq2_o = alloc(HID), sum4_o = alloc(HID), sq4_o = alloc(HID);
  size_t hmax_o = alloc(HID);
  size_t zero_end = o;                       // everything above must be zeroed
  size_t A12_o = alloc(HID), C12_o = alloc(HID), A34_o = alloc(HID), C34_o = alloc(HID);
  size_t Aq_o = alloc(HID), qinv_o = alloc(HID);
  size_t rowptr_o = alloc(n + 1);
  size_t cursor_o = alloc(n + 1);
  size_t bsum_o = alloc(64);
  size_t emb1b_o = alloc(65 * HID / 2);      // bf16 pairs
  size_t sedge_o = alloc((size_t)e * 2);     // int2 per edge
  size_t h2b_o = alloc((size_t)n * HID / 2); // bf16 pairs (uint) per 2 elements
  size_t qmat_o = alloc((size_t)n * HID / 4); // int8 per element (uint per 4)

  int* cnt = (int*)(wsf + cnt_o);
  int* hist = (int*)(wsf + hist_o);
  float* sum2 = wsf + sum2_o; float* sq2 = wsf + sq2_o;
  float* sum4 = wsf + sum4_o; float* sq4 = wsf + sq4_o;
  unsigned* hmax = (unsigned*)(wsf + hmax_o);
  float* A12 = wsf + A12_o; float* C12 = wsf + C12_o;
  float* A34 = wsf + A34_o; float* C34 = wsf + C34_o;
  float* Aq = wsf + Aq_o; float* qinv = wsf + qinv_o;
  int* rowptr = (int*)(wsf + rowptr_o);
  int* cursor = (int*)(wsf + cursor_o);
  int* bsum = (int*)(wsf + bsum_o);
  unsigned* emb1b = (unsigned*)(wsf + emb1b_o);
  int2* sedge = (int2*)(wsf + sedge_o);
  unsigned* h2b = (unsigned*)(wsf + h2b_o);
  unsigned* qmat = (unsigned*)(wsf + qmat_o);

  const float invN = 1.0f / (float)n;
  const int nblk = 2048;
  const int nwaves = nblk * 4;

  hipMemsetAsync(d_ws, 0, zero_end * sizeof(float), stream);
  k_histcnt<<<2048, 256, 0, stream>>>(x, n, row, e, hist, cnt);
  int nb = (n + 1 + 2047) / 2048;
  k_scan_partial<<<nb, 256, 0, stream>>>(cnt, n + 1, bsum);
  k_scan_bsum<<<1, 64, 0, stream>>>(bsum, nb);
  k_scan_final<<<nb, 256, 0, stream>>>(cnt, n + 1, bsum, rowptr, cursor);
  k_scatter<<<2048, 256, 0, stream>>>(row, col, ew, x, e, cursor, sedge);
  k_gn0<<<1, 64, 0, stream>>>(emb, hist, gw, gb, gms, invN, emb1b);
  k_spmm1<<<nblk, 256, 0, stream>>>(rowptr, sedge, emb1b, n, nwaves, h2b, sum2, sq2, hmax);
  k_gnchain<<<1, HID, 0, stream>>>(sum2, sq2, invN, gw, gb, gms, 1, 2, A12, C12,
                                   (const float*)hmax, Aq, qinv);
  k_quant<<<2048, 256, 0, stream>>>(h2b, qinv, n, qmat);
  k_spmm2<<<nblk, 256, 0, stream>>>(rowptr, sedge, (const unsigned char*)qmat, Aq, C12,
                                    n, nwaves, out, sum4, sq4);
  k_gnchain<<<1, HID, 0, stream>>>(sum4, sq4, invN, gw, gb, gms, 3, 4, A34, C34,
                                   nullptr, nullptr, nullptr);
  k_final<<<2048, 256, 0, stream>>>(out, A34, C34, n);
}

// Round 9
// 515.135 us; speedup vs baseline: 2.0837x; 1.1402x over previous
//
#include <hip/hip_runtime.h>

#define HID 128
#define EPSF 1e-6f

__device__ inline unsigned f2bf(float f) {
  unsigned u = __float_as_uint(f);
  return (u + 0x7fffu + ((u >> 16) & 1u)) >> 16;  // RNE
}
__device__ inline float bf2f_lo(unsigned u) { return __uint_as_float(u << 16); }
__device__ inline float bf2f_hi(unsigned u) { return __uint_as_float(u & 0xFFFF0000u); }

// ------- fused: histogram of x (65 bins) + per-row edge count + slot capture -------
__global__ void k_histcnt(const int* __restrict__ x, int n, const int* __restrict__ row,
                          int e, int* __restrict__ hist, int* __restrict__ cnt,
                          int* __restrict__ slot) {
  __shared__ int lh[65];
  int t = threadIdx.x;
  if (t < 65) lh[t] = 0;
  __syncthreads();
  int tid = blockIdx.x * blockDim.x + t, stride = gridDim.x * blockDim.x;
  for (int i = tid; i < e; i += stride) slot[i] = atomicAdd(&cnt[row[i]], 1);
  for (int i = tid; i < n; i += stride) atomicAdd(&lh[x[i]], 1);
  __syncthreads();
  if (t < 65 && lh[t]) atomicAdd(&hist[t], lh[t]);
}

// ---------------- 3-phase exclusive scan over cnt[0..n) -> rowptr ----------------
__global__ void k_scan_partial(const int* __restrict__ cnt, int n, int* __restrict__ bsum) {
  __shared__ int sh[256];
  int t = threadIdx.x;
  int base = blockIdx.x * 2048 + t * 8;
  int s = 0;
#pragma unroll
  for (int j = 0; j < 8; ++j) { int idx = base + j; if (idx < n) s += cnt[idx]; }
  sh[t] = s; __syncthreads();
  for (int off = 128; off > 0; off >>= 1) {
    if (t < off) sh[t] += sh[t + off];
    __syncthreads();
  }
  if (t == 0) bsum[blockIdx.x] = sh[0];
}

__global__ void k_scan_bsum(int* __restrict__ bsum, int nb) {
  if (threadIdx.x == 0 && blockIdx.x == 0) {
    int acc = 0;
    for (int i = 0; i < nb; ++i) { int v = bsum[i]; bsum[i] = acc; acc += v; }
  }
}

__global__ void k_scan_final(const int* __restrict__ cnt, int n, const int* __restrict__ bsum,
                             int* __restrict__ rowptr) {
  __shared__ int sh[256];
  int t = threadIdx.x;
  int base = blockIdx.x * 2048 + t * 8;
  int v[8]; int s = 0;
#pragma unroll
  for (int j = 0; j < 8; ++j) { int idx = base + j; v[j] = (idx < n) ? cnt[idx] : 0; s += v[j]; }
  sh[t] = s; __syncthreads();
  for (int off = 1; off < 256; off <<= 1) {
    int val = (t >= off) ? sh[t - off] : 0;
    __syncthreads();
    sh[t] += val;
    __syncthreads();
  }
  int off0 = bsum[blockIdx.x] + sh[t] - s;  // exclusive prefix for this thread
#pragma unroll
  for (int j = 0; j < 8; ++j) {
    int idx = base + j;
    if (idx < n) { rowptr[idx] = off0; off0 += v[j]; }
  }
}

// ------- scatter edges into CSR order: atomic-free, pos = rowptr[r] + slot[i] -------
__global__ __launch_bounds__(256) void k_scatter(
    const int* __restrict__ row, const int* __restrict__ col,
    const float* __restrict__ ew, const int* __restrict__ x,
    const int* __restrict__ rowptr, const int* __restrict__ slot, int e,
    int2* __restrict__ sedge) {
  int tid = blockIdx.x * blockDim.x + threadIdx.x;
  int stride = gridDim.x * blockDim.x;
  for (int i0 = tid; i0 < e; i0 += stride * 4) {
    int r[4], c[4], s[4], xc[4], rp[4]; float w[4]; bool valid[4];
#pragma unroll
    for (int k = 0; k < 4; ++k) {
      int i = i0 + k * stride; valid[k] = (i < e);
      if (valid[k]) { r[k] = row[i]; c[k] = col[i]; w[k] = ew[i]; s[k] = slot[i]; }
    }
#pragma unroll
    for (int k = 0; k < 4; ++k) if (valid[k]) { xc[k] = x[c[k]]; rp[k] = rowptr[r[k]]; }
#pragma unroll
    for (int k = 0; k < 4; ++k)
      if (valid[k]) sedge[rp[k] + s[k]] = make_int2(c[k] | (xc[k] << 17), __float_as_int(w[k]));
  }
}

// ---------------- fold GN0 into bf16-packed embedding table ----------------
__global__ void k_gn0(const float* __restrict__ emb, const int* __restrict__ hist,
                      const float* __restrict__ gw, const float* __restrict__ gb,
                      const float* __restrict__ gms, float invN,
                      unsigned* __restrict__ emb1b) {
  int t = threadIdx.x;  // 64 threads; cols d0=2t, d1=2t+1
  int d0 = t * 2, d1 = t * 2 + 1;
  float s0 = 0, s20 = 0, s1 = 0, s21 = 0;
  for (int k = 0; k < 65; ++k) {
    float c = (float)hist[k];
    float v0 = emb[k * HID + d0], v1 = emb[k * HID + d1];
    s0 += c * v0; s20 += c * v0 * v0;
    s1 += c * v1; s21 += c * v1 * v1;
  }
  float m0 = s0 * invN, E20 = s20 * invN;
  float m1 = s1 * invN, E21 = s21 * invN;
  float sh0 = m0 * gms[d0], sh1 = m1 * gms[d1];
  float aa0 = gw[d0] / sqrtf(E20 - 2.f * sh0 * m0 + sh0 * sh0 + EPSF);
  float aa1 = gw[d1] / sqrtf(E21 - 2.f * sh1 * m1 + sh1 * sh1 + EPSF);
  float cc0 = gb[d0] - aa0 * sh0, cc1 = gb[d1] - aa1 * sh1;
  for (int k = 0; k < 65; ++k) {
    float y0 = fmaf(aa0, emb[k * HID + d0], cc0);
    float y1 = fmaf(aa1, emb[k * HID + d1], cc1);
    emb1b[k * (HID / 2) + t] = f2bf(y0) | (f2bf(y1) << 16);
  }
}

// ---- chained double-GraphNorm -> affine; optionally fold int8 dequant scale --------
__global__ void k_gnchain(const float* __restrict__ gsum, const float* __restrict__ gsq,
                          float invN, const float* __restrict__ gw, const float* __restrict__ gb,
                          const float* __restrict__ gms, int i1, int i2,
                          float* __restrict__ A, float* __restrict__ C,
                          const float* __restrict__ hmax, float* __restrict__ Aq,
                          float* __restrict__ qinv) {
  int d = threadIdx.x;  // 128 threads
  float m = gsum[d] * invN, E2 = gsq[d] * invN;
  float ms1 = gms[i1 * HID + d], w1 = gw[i1 * HID + d], b1 = gb[i1 * HID + d];
  float sh1 = m * ms1;
  float a1 = w1 / sqrtf(E2 - 2.f * sh1 * m + sh1 * sh1 + EPSF);
  float c1 = b1 - a1 * sh1;
  float m2 = a1 * m + c1;
  float E2b = a1 * a1 * E2 + 2.f * a1 * c1 * m + c1 * c1;
  float ms2 = gms[i2 * HID + d], w2 = gw[i2 * HID + d], b2 = gb[i2 * HID + d];
  float sh2 = m2 * ms2;
  float a2 = w2 / sqrtf(E2b - 2.f * sh2 * m2 + sh2 * sh2 + EPSF);
  float c2 = b2 - a2 * sh2;
  float Af = a2 * a1, Cf = a2 * c1 + c2;
  A[d] = Af; C[d] = Cf;
  if (hmax) {
    float h = hmax[d];                       // max |h2| per column (bf16-rounded domain)
    Aq[d] = Af * (h * (1.0f / 127.0f));      // dequant folded into affine
    qinv[d] = (h > 0.f) ? 127.0f / h : 0.f;
  }
}

// ============ SpMM1: wave-per-node, bf16 LDS table (16.6 KB), fused hmax ============
__global__ __launch_bounds__(256) void k_spmm1(
    const int* __restrict__ rowptr, const int2* __restrict__ sedge,
    const unsigned* __restrict__ emb1b, int n, int nwaves,
    unsigned* __restrict__ h2b, float* __restrict__ gsum, float* __restrict__ gsq,
    unsigned* __restrict__ hmax) {
  __shared__ unsigned lemb[65 * 64];
  __shared__ float red[2][4][64][2];
  __shared__ float rmx[4][64][2];
  int t = threadIdx.x;
  for (int i = t; i < 65 * 64; i += 256) lemb[i] = emb1b[i];
  __syncthreads();
  int l = t & 63, wv = t >> 6;
  int gwid = blockIdx.x * 4 + wv;
  float ps0 = 0, ps1 = 0, q0s = 0, q1s = 0, m0 = 0, m1 = 0;
  for (int node = gwid; node < n; node += nwaves) {
    int nd = __builtin_amdgcn_readfirstlane(node);
    int p0 = rowptr[nd], p1 = rowptr[nd + 1];
    float wsum = 0.f, a0 = 0.f, a1 = 0.f;
    int p = p0;
    int nfull = p0 + ((p1 - p0) & ~7);
    for (; p < nfull; p += 8) {
      int2 b[8];
#pragma unroll
      for (int k = 0; k < 8; ++k) b[k] = sedge[p + k];
#pragma unroll
      for (int k = 0; k < 8; ++k) {
        unsigned v = lemb[(unsigned)(b[k].x >> 17) * 64 + l];
        float w = __int_as_float(b[k].y);
        wsum += w;
        a0 = fmaf(w, bf2f_lo(v), a0);
        a1 = fmaf(w, bf2f_hi(v), a1);
      }
    }
    for (; p < p1; ++p) {
      int2 b = sedge[p];
      unsigned v = lemb[(unsigned)(b.x >> 17) * 64 + l];
      float w = __int_as_float(b.y);
      wsum += w;
      a0 = fmaf(w, bf2f_lo(v), a0);
      a1 = fmaf(w, bf2f_hi(v), a1);
    }
    float d = (wsum < 0.5f) ? wsum + 1.0f : wsum;
    float invd = 1.0f / d;
    a0 *= invd; a1 *= invd;
    unsigned b0 = f2bf(a0), b1 = f2bf(a1);
    h2b[(size_t)node * 64 + l] = b0 | (b1 << 16);
    m0 = fmaxf(m0, fabsf(__uint_as_float(b0 << 16)));  // max over the STORED (rounded) values
    m1 = fmaxf(m1, fabsf(__uint_as_float(b1 << 16)));
    ps0 += a0; ps1 += a1; q0s += a0 * a0; q1s += a1 * a1;
  }
  red[0][wv][l][0] = ps0; red[0][wv][l][1] = ps1;
  red[1][wv][l][0] = q0s; red[1][wv][l][1] = q1s;
  rmx[wv][l][0] = m0; rmx[wv][l][1] = m1;
  __syncthreads();
  if (wv == 0) {
    float s0 = 0, s1 = 0, t0 = 0, t1 = 0, x0 = 0, x1 = 0;
#pragma unroll
    for (int k = 0; k < 4; ++k) {
      s0 += red[0][k][l][0]; s1 += red[0][k][l][1];
      t0 += red[1][k][l][0]; t1 += red[1][k][l][1];
      x0 = fmaxf(x0, rmx[k][l][0]); x1 = fmaxf(x1, rmx[k][l][1]);
    }
    atomicAdd(&gsum[l * 2], s0); atomicAdd(&gsum[l * 2 + 1], s1);
    atomicAdd(&gsq[l * 2], t0);  atomicAdd(&gsq[l * 2 + 1], t1);
    atomicMax(&hmax[l * 2], __float_as_uint(x0));       // positive floats order as uints
    atomicMax(&hmax[l * 2 + 1], __float_as_uint(x1));
  }
}

// ---------------- quantize h2 (bf16) -> int8 per-column scale ----------------
__global__ __launch_bounds__(256) void k_quant(const unsigned* __restrict__ h2b,
                                               const float* __restrict__ qinv, int n,
                                               unsigned* __restrict__ qmat) {
  int stride = gridDim.x * blockDim.x;
  int total = n * 32;  // 4-col groups
  for (int idx = blockIdx.x * blockDim.x + threadIdx.x; idx < total; idx += stride) {
    int node = idx >> 5, g = idx & 31;
    const unsigned* src = &h2b[(size_t)node * 64 + g * 2];
    unsigned v0 = src[0], v1 = src[1];
    float4 qv = *(const float4*)&qinv[g * 4];
    int c0 = (int)rintf(bf2f_lo(v0) * qv.x);
    int c1 = (int)rintf(bf2f_hi(v0) * qv.y);
    int c2 = (int)rintf(bf2f_lo(v1) * qv.z);
    int c3 = (int)rintf(bf2f_hi(v1) * qv.w);
    qmat[idx] = (unsigned)(c0 & 0xFF) | ((unsigned)(c1 & 0xFF) << 8) |
                ((unsigned)(c2 & 0xFF) << 16) | ((unsigned)(c3 & 0xFF) << 24);
  }
}

// ============ SpMM2: wave-per-node, int8 gathers (128 B/row = 2 lines) ==============
__global__ __launch_bounds__(256) void k_spmm2(
    const int* __restrict__ rowptr, const int2* __restrict__ sedge,
    const unsigned char* __restrict__ qmat,
    const float* __restrict__ Aq, const float* __restrict__ C,
    int n, int nwaves, float* __restrict__ out,
    float* __restrict__ gsum, float* __restrict__ gsq) {
  __shared__ float red[2][4][64][2];
  int t = threadIdx.x;
  int l = t & 63, wv = t >> 6;
  int gwid = blockIdx.x * 4 + wv;
  float A0 = Aq[l * 2], A1 = Aq[l * 2 + 1], C0 = C[l * 2], C1 = C[l * 2 + 1];
  float ps0 = 0, ps1 = 0, q0s = 0, q1s = 0;
  for (int node = gwid; node < n; node += nwaves) {
    int nd = __builtin_amdgcn_readfirstlane(node);
    int p0 = rowptr[nd], p1 = rowptr[nd + 1];
    float wsum = 0.f, a0 = 0.f, a1 = 0.f;
    int p = p0;
    int nfull = p0 + ((p1 - p0) & ~7);
    for (; p < nfull; p += 8) {
      int2 b[8];
#pragma unroll
      for (int k = 0; k < 8; ++k) b[k] = sedge[p + k];
      unsigned short u[8];
#pragma unroll
      for (int k = 0; k < 8; ++k)
        u[k] = *(const unsigned short*)&qmat[(size_t)(b[k].x & 0x1FFFF) * 128 + l * 2];
#pragma unroll
      for (int k = 0; k < 8; ++k) {
        float w = __int_as_float(b[k].y);
        wsum += w;
        float y0 = fmaxf(fmaf(A0, (float)(signed char)(u[k] & 0xFF), C0), 0.f);
        float y1 = fmaxf(fmaf(A1, (float)(signed char)(u[k] >> 8), C1), 0.f);
        a0 = fmaf(w, y0, a0);
        a1 = fmaf(w, y1, a1);
      }
    }
    for (; p < p1; ++p) {
      int2 b = sedge[p];
      unsigned short u = *(const unsigned short*)&qmat[(size_t)(b.x & 0x1FFFF) * 128 + l * 2];
      float w = __int_as_float(b.y);
      wsum += w;
      float y0 = fmaxf(fmaf(A0, (float)(signed char)(u & 0xFF), C0), 0.f);
      float y1 = fmaxf(fmaf(A1, (float)(signed char)(u >> 8), C1), 0.f);
      a0 = fmaf(w, y0, a0);
      a1 = fmaf(w, y1, a1);
    }
    float d = (wsum < 0.5f) ? wsum + 1.0f : wsum;
    float invd = 1.0f / d;
    a0 *= invd; a1 *= invd;
    *(float2*)&out[(size_t)node * HID + l * 2] = make_float2(a0, a1);
    ps0 += a0; ps1 += a1; q0s += a0 * a0; q1s += a1 * a1;
  }
  red[0][wv][l][0] = ps0; red[0][wv][l][1] = ps1;
  red[1][wv][l][0] = q0s; red[1][wv][l][1] = q1s;
  __syncthreads();
  if (wv == 0) {
    float s0 = 0, s1 = 0, t0 = 0, t1 = 0;
#pragma unroll
    for (int k = 0; k < 4; ++k) {
      s0 += red[0][k][l][0]; s1 += red[0][k][l][1];
      t0 += red[1][k][l][0]; t1 += red[1][k][l][1];
    }
    atomicAdd(&gsum[l * 2], s0); atomicAdd(&gsum[l * 2 + 1], s1);
    atomicAdd(&gsq[l * 2], t0);  atomicAdd(&gsq[l * 2 + 1], t1);
  }
}

// ---------------- final in-place affine on d_out ----------------
__global__ void k_final(float* __restrict__ out, const float* __restrict__ A,
                        const float* __restrict__ C, int n) {
  __shared__ float la[HID], lc[HID];
  if (threadIdx.x < HID) { la[threadIdx.x] = A[threadIdx.x]; lc[threadIdx.x] = C[threadIdx.x]; }
  __syncthreads();
  int total = n * 32;  // float4 count
  for (int i = blockIdx.x * blockDim.x + threadIdx.x; i < total; i += gridDim.x * blockDim.x) {
    float4 v = *(float4*)(out + (size_t)i * 4);
    int cg = (i & 31) * 4;
    v.x = fmaf(la[cg + 0], v.x, lc[cg + 0]);
    v.y = fmaf(la[cg + 1], v.y, lc[cg + 1]);
    v.z = fmaf(la[cg + 2], v.z, lc[cg + 2]);
    v.w = fmaf(la[cg + 3], v.w, lc[cg + 3]);
    *(float4*)(out + (size_t)i * 4) = v;
  }
}

extern "C" void kernel_launch(void* const* d_in, const int* in_sizes, int n_in,
                              void* d_out, int out_size, void* d_ws, size_t ws_size,
                              hipStream_t stream) {
  const int* x = (const int*)d_in[0];
  const int* ei = (const int*)d_in[1];
  const float* ew = (const float*)d_in[2];
  const float* emb = (const float*)d_in[3];
  const float* gw = (const float*)d_in[4];
  const float* gb = (const float*)d_in[5];
  const float* gms = (const float*)d_in[6];
  float* out = (float*)d_out;

  const int n = in_sizes[0];        // 100000
  const int e = in_sizes[1] / 2;    // 1600000
  const int* row = ei;
  const int* col = ei + e;

  // workspace layout, in 4-byte units, 128B-aligned chunks
  float* wsf = (float*)d_ws;
  size_t o = 0;
  auto alloc = [&](size_t elems) -> size_t { size_t r = o; o += ((elems + 31) & ~(size_t)31); return r; };
  size_t cnt_o = alloc(n + 1);
  size_t hist_o = alloc(65);
  size_t sum2_o = alloc(HID), sq2_o = alloc(HID), sum4_o = alloc(HID), sq4_o = alloc(HID);
  size_t hmax_o = alloc(HID);
  size_t zero_end = o;                       // everything above must be zeroed
  size_t A12_o = alloc(HID), C12_o = alloc(HID), A34_o = alloc(HID), C34_o = alloc(HID);
  size_t Aq_o = alloc(HID), qinv_o = alloc(HID);
  size_t rowptr_o = alloc(n + 1);
  size_t slot_o = alloc(e);
  size_t bsum_o = alloc(64);
  size_t emb1b_o = alloc(65 * HID / 2);      // bf16 pairs
  size_t sedge_o = alloc((size_t)e * 2);     // int2 per edge
  size_t h2b_o = alloc((size_t)n * HID / 2); // bf16 pairs (uint) per 2 elements
  size_t qmat_o = alloc((size_t)n * HID / 4); // int8 per element (uint per 4)

  int* cnt = (int*)(wsf + cnt_o);
  int* hist = (int*)(wsf + hist_o);
  float* sum2 = wsf + sum2_o; float* sq2 = wsf + sq2_o;
  float* sum4 = wsf + sum4_o; float* sq4 = wsf + sq4_o;
  unsigned* hmax = (unsigned*)(wsf + hmax_o);
  float* A12 = wsf + A12_o; float* C12 = wsf + C12_o;
  float* A34 = wsf + A34_o; float* C34 = wsf + C34_o;
  float* Aq = wsf + Aq_o; float* qinv = wsf + qinv_o;
  int* rowptr = (int*)(wsf + rowptr_o);
  int* slot = (int*)(wsf + slot_o);
  int* bsum = (int*)(wsf + bsum_o);
  unsigned* emb1b = (unsigned*)(wsf + emb1b_o);
  int2* sedge = (int2*)(wsf + sedge_o);
  unsigned* h2b = (unsigned*)(wsf + h2b_o);
  unsigned* qmat = (unsigned*)(wsf + qmat_o);

  const float invN = 1.0f / (float)n;
  const int nblk = 2048;
  const int nwaves = nblk * 4;

  hipMemsetAsync(d_ws, 0, zero_end * sizeof(float), stream);
  k_histcnt<<<2048, 256, 0, stream>>>(x, n, row, e, hist, cnt, slot);
  int nb = (n + 1 + 2047) / 2048;
  k_scan_partial<<<nb, 256, 0, stream>>>(cnt, n + 1, bsum);
  k_scan_bsum<<<1, 64, 0, stream>>>(bsum, nb);
  k_scan_final<<<nb, 256, 0, stream>>>(cnt, n + 1, bsum, rowptr);
  k_scatter<<<2048, 256, 0, stream>>>(row, col, ew, x, rowptr, slot, e, sedge);
  k_gn0<<<1, 64, 0, stream>>>(emb, hist, gw, gb, gms, invN, emb1b);
  k_spmm1<<<nblk, 256, 0, stream>>>(rowptr, sedge, emb1b, n, nwaves, h2b, sum2, sq2, hmax);
  k_gnchain<<<1, HID, 0, stream>>>(sum2, sq2, invN, gw, gb, gms, 1, 2, A12, C12,
                                   (const float*)hmax, Aq, qinv);
  k_quant<<<2048, 256, 0, stream>>>(h2b, qinv, n, qmat);
  k_spmm2<<<nblk, 256, 0, stream>>>(rowptr, sedge, (const unsigned char*)qmat, Aq, C12,
                                    n, nwaves, out, sum4, sq4);
  k_gnchain<<<1, HID, 0, stream>>>(sum4, sq4, invN, gw, gb, gms, 3, 4, A34, C34,
                                   nullptr, nullptr, nullptr);
  k_final<<<2048, 256, 0, stream>>>(out, A34, C34, n);
}

// Round 10
// 496.588 us; speedup vs baseline: 2.1615x; 1.0374x over previous
//
#include <hip/hip_runtime.h>

#define HID 128
#define EPSF 1e-6f

__device__ inline unsigned f2bf(float f) {
  unsigned u = __float_as_uint(f);
  return (u + 0x7fffu + ((u >> 16) & 1u)) >> 16;  // RNE
}
__device__ inline float bf2f_lo(unsigned u) { return __uint_as_float(u << 16); }
__device__ inline float bf2f_hi(unsigned u) { return __uint_as_float(u & 0xFFFF0000u); }

// ------- fused: histogram of x (65 bins) + per-row edge count + slot capture -------
__global__ void k_histcnt(const int* __restrict__ x, int n, const int* __restrict__ row,
                          int e, int* __restrict__ hist, int* __restrict__ cnt,
                          int* __restrict__ slot) {
  __shared__ int lh[65];
  int t = threadIdx.x;
  if (t < 65) lh[t] = 0;
  __syncthreads();
  int tid = blockIdx.x * blockDim.x + t, stride = gridDim.x * blockDim.x;
  for (int i = tid; i < e; i += stride) slot[i] = atomicAdd(&cnt[row[i]], 1);
  for (int i = tid; i < n; i += stride) atomicAdd(&lh[x[i]], 1);
  __syncthreads();
  if (t < 65 && lh[t]) atomicAdd(&hist[t], lh[t]);
}

// ---------------- 3-phase exclusive scan over cnt[0..n) -> rowptr ----------------
__global__ void k_scan_partial(const int* __restrict__ cnt, int n, int* __restrict__ bsum) {
  __shared__ int sh[256];
  int t = threadIdx.x;
  int base = blockIdx.x * 2048 + t * 8;
  int s = 0;
#pragma unroll
  for (int j = 0; j < 8; ++j) { int idx = base + j; if (idx < n) s += cnt[idx]; }
  sh[t] = s; __syncthreads();
  for (int off = 128; off > 0; off >>= 1) {
    if (t < off) sh[t] += sh[t + off];
    __syncthreads();
  }
  if (t == 0) bsum[blockIdx.x] = sh[0];
}

__global__ void k_scan_bsum(int* __restrict__ bsum, int nb) {
  if (threadIdx.x == 0 && blockIdx.x == 0) {
    int acc = 0;
    for (int i = 0; i < nb; ++i) { int v = bsum[i]; bsum[i] = acc; acc += v; }
  }
}

__global__ void k_scan_final(const int* __restrict__ cnt, int n, const int* __restrict__ bsum,
                             int* __restrict__ rowptr) {
  __shared__ int sh[256];
  int t = threadIdx.x;
  int base = blockIdx.x * 2048 + t * 8;
  int v[8]; int s = 0;
#pragma unroll
  for (int j = 0; j < 8; ++j) { int idx = base + j; v[j] = (idx < n) ? cnt[idx] : 0; s += v[j]; }
  sh[t] = s; __syncthreads();
  for (int off = 1; off < 256; off <<= 1) {
    int val = (t >= off) ? sh[t - off] : 0;
    __syncthreads();
    sh[t] += val;
    __syncthreads();
  }
  int off0 = bsum[blockIdx.x] + sh[t] - s;  // exclusive prefix for this thread
#pragma unroll
  for (int j = 0; j < 8; ++j) {
    int idx = base + j;
    if (idx < n) { rowptr[idx] = off0; off0 += v[j]; }
  }
}

// ------- scatter edges into CSR order: atomic-free, pos = rowptr[r] + slot[i] -------
__global__ __launch_bounds__(256) void k_scatter(
    const int* __restrict__ row, const int* __restrict__ col,
    const float* __restrict__ ew, const int* __restrict__ x,
    const int* __restrict__ rowptr, const int* __restrict__ slot, int e,
    int2* __restrict__ sedge) {
  int tid = blockIdx.x * blockDim.x + threadIdx.x;
  int stride = gridDim.x * blockDim.x;
  for (int i0 = tid; i0 < e; i0 += stride * 4) {
    int r[4], c[4], s[4], xc[4], rp[4]; float w[4]; bool valid[4];
#pragma unroll
    for (int k = 0; k < 4; ++k) {
      int i = i0 + k * stride; valid[k] = (i < e);
      if (valid[k]) { r[k] = row[i]; c[k] = col[i]; w[k] = ew[i]; s[k] = slot[i]; }
    }
#pragma unroll
    for (int k = 0; k < 4; ++k) if (valid[k]) { xc[k] = x[c[k]]; rp[k] = rowptr[r[k]]; }
#pragma unroll
    for (int k = 0; k < 4; ++k)
      if (valid[k]) sedge[rp[k] + s[k]] = make_int2(c[k] | (xc[k] << 17), __float_as_int(w[k]));
  }
}

// ---------------- fold GN0 into bf16-packed embedding table ----------------
__global__ void k_gn0(const float* __restrict__ emb, const int* __restrict__ hist,
                      const float* __restrict__ gw, const float* __restrict__ gb,
                      const float* __restrict__ gms, float invN,
                      unsigned* __restrict__ emb1b) {
  int t = threadIdx.x;  // 64 threads; cols d0=2t, d1=2t+1
  int d0 = t * 2, d1 = t * 2 + 1;
  float s0 = 0, s20 = 0, s1 = 0, s21 = 0;
  for (int k = 0; k < 65; ++k) {
    float c = (float)hist[k];
    float v0 = emb[k * HID + d0], v1 = emb[k * HID + d1];
    s0 += c * v0; s20 += c * v0 * v0;
    s1 += c * v1; s21 += c * v1 * v1;
  }
  float m0 = s0 * invN, E20 = s20 * invN;
  float m1 = s1 * invN, E21 = s21 * invN;
  float sh0 = m0 * gms[d0], sh1 = m1 * gms[d1];
  float aa0 = gw[d0] / sqrtf(E20 - 2.f * sh0 * m0 + sh0 * sh0 + EPSF);
  float aa1 = gw[d1] / sqrtf(E21 - 2.f * sh1 * m1 + sh1 * sh1 + EPSF);
  float cc0 = gb[d0] - aa0 * sh0, cc1 = gb[d1] - aa1 * sh1;
  for (int k = 0; k < 65; ++k) {
    float y0 = fmaf(aa0, emb[k * HID + d0], cc0);
    float y1 = fmaf(aa1, emb[k * HID + d1], cc1);
    emb1b[k * (HID / 2) + t] = f2bf(y0) | (f2bf(y1) << 16);
  }
}

// ---- chained double-GraphNorm -> affine; optionally fold int8 dequant scale --------
__global__ void k_gnchain(const float* __restrict__ gsum, const float* __restrict__ gsq,
                          float invN, const float* __restrict__ gw, const float* __restrict__ gb,
                          const float* __restrict__ gms, int i1, int i2,
                          float* __restrict__ A, float* __restrict__ C,
                          const float* __restrict__ hmax, float* __restrict__ Aq,
                          float* __restrict__ qinv) {
  int d = threadIdx.x;  // 128 threads
  float m = gsum[d] * invN, E2 = gsq[d] * invN;
  float ms1 = gms[i1 * HID + d], w1 = gw[i1 * HID + d], b1 = gb[i1 * HID + d];
  float sh1 = m * ms1;
  float a1 = w1 / sqrtf(E2 - 2.f * sh1 * m + sh1 * sh1 + EPSF);
  float c1 = b1 - a1 * sh1;
  float m2 = a1 * m + c1;
  float E2b = a1 * a1 * E2 + 2.f * a1 * c1 * m + c1 * c1;
  float ms2 = gms[i2 * HID + d], w2 = gw[i2 * HID + d], b2 = gb[i2 * HID + d];
  float sh2 = m2 * ms2;
  float a2 = w2 / sqrtf(E2b - 2.f * sh2 * m2 + sh2 * sh2 + EPSF);
  float c2 = b2 - a2 * sh2;
  float Af = a2 * a1, Cf = a2 * c1 + c2;
  A[d] = Af; C[d] = Cf;
  if (hmax) {
    float h = hmax[d];                       // max |h2| per column (bf16-rounded domain)
    Aq[d] = Af * (h * (1.0f / 127.0f));      // dequant folded into affine
    qinv[d] = (h > 0.f) ? 127.0f / h : 0.f;
  }
}

// ====== SpMM1: wave-per-node, bf16 LDS table, batch-16 clamped epochs, fused hmax ====
__global__ __launch_bounds__(256) void k_spmm1(
    const int* __restrict__ rowptr, const int2* __restrict__ sedge,
    const unsigned* __restrict__ emb1b, int n, int nwaves,
    unsigned* __restrict__ h2b, float* __restrict__ gsum, float* __restrict__ gsq,
    unsigned* __restrict__ hmax) {
  __shared__ unsigned lemb[65 * 64];
  __shared__ float red[2][4][64][2];
  __shared__ float rmx[4][64][2];
  int t = threadIdx.x;
  for (int i = t; i < 65 * 64; i += 256) lemb[i] = emb1b[i];
  __syncthreads();
  int l = t & 63, wv = t >> 6;
  int gwid = blockIdx.x * 4 + wv;
  float ps0 = 0, ps1 = 0, q0s = 0, q1s = 0, m0 = 0, m1 = 0;
  for (int node = gwid; node < n; node += nwaves) {
    int nd = __builtin_amdgcn_readfirstlane(node);
    int p0 = rowptr[nd], p1 = rowptr[nd + 1];
    float wsum = 0.f, a0 = 0.f, a1 = 0.f;
    for (int base = p0; base < p1; base += 16) {
      int2 b[16]; float w[16];
#pragma unroll
      for (int k = 0; k < 16; ++k) {
        int idx = base + k;
        b[k] = sedge[idx < p1 ? idx : p1 - 1];
      }
#pragma unroll
      for (int k = 0; k < 16; ++k)
        w[k] = (base + k < p1) ? __int_as_float(b[k].y) : 0.f;
#pragma unroll
      for (int k = 0; k < 16; ++k) {
        unsigned v = lemb[(unsigned)(b[k].x >> 17) * 64 + l];
        wsum += w[k];
        a0 = fmaf(w[k], bf2f_lo(v), a0);
        a1 = fmaf(w[k], bf2f_hi(v), a1);
      }
    }
    float d = (wsum < 0.5f) ? wsum + 1.0f : wsum;
    float invd = 1.0f / d;
    a0 *= invd; a1 *= invd;
    unsigned b0 = f2bf(a0), b1 = f2bf(a1);
    h2b[(size_t)node * 64 + l] = b0 | (b1 << 16);
    m0 = fmaxf(m0, fabsf(__uint_as_float(b0 << 16)));  // max over the STORED (rounded) values
    m1 = fmaxf(m1, fabsf(__uint_as_float(b1 << 16)));
    ps0 += a0; ps1 += a1; q0s += a0 * a0; q1s += a1 * a1;
  }
  red[0][wv][l][0] = ps0; red[0][wv][l][1] = ps1;
  red[1][wv][l][0] = q0s; red[1][wv][l][1] = q1s;
  rmx[wv][l][0] = m0; rmx[wv][l][1] = m1;
  __syncthreads();
  if (wv == 0) {
    float s0 = 0, s1 = 0, t0 = 0, t1 = 0, x0 = 0, x1 = 0;
#pragma unroll
    for (int k = 0; k < 4; ++k) {
      s0 += red[0][k][l][0]; s1 += red[0][k][l][1];
      t0 += red[1][k][l][0]; t1 += red[1][k][l][1];
      x0 = fmaxf(x0, rmx[k][l][0]); x1 = fmaxf(x1, rmx[k][l][1]);
    }
    atomicAdd(&gsum[l * 2], s0); atomicAdd(&gsum[l * 2 + 1], s1);
    atomicAdd(&gsq[l * 2], t0);  atomicAdd(&gsq[l * 2 + 1], t1);
    atomicMax(&hmax[l * 2], __float_as_uint(x0));       // positive floats order as uints
    atomicMax(&hmax[l * 2 + 1], __float_as_uint(x1));
  }
}

// ---------------- quantize h2 (bf16) -> int8 per-column scale ----------------
__global__ __launch_bounds__(256) void k_quant(const unsigned* __restrict__ h2b,
                                               const float* __restrict__ qinv, int n,
                                               unsigned* __restrict__ qmat) {
  int stride = gridDim.x * blockDim.x;
  int total = n * 32;  // 4-col groups
  for (int idx = blockIdx.x * blockDim.x + threadIdx.x; idx < total; idx += stride) {
    int node = idx >> 5, g = idx & 31;
    const unsigned* src = &h2b[(size_t)node * 64 + g * 2];
    unsigned v0 = src[0], v1 = src[1];
    float4 qv = *(const float4*)&qinv[g * 4];
    int c0 = (int)rintf(bf2f_lo(v0) * qv.x);
    int c1 = (int)rintf(bf2f_hi(v0) * qv.y);
    int c2 = (int)rintf(bf2f_lo(v1) * qv.z);
    int c3 = (int)rintf(bf2f_hi(v1) * qv.w);
    qmat[idx] = (unsigned)(c0 & 0xFF) | ((unsigned)(c1 & 0xFF) << 8) |
                ((unsigned)(c2 & 0xFF) << 16) | ((unsigned)(c3 & 0xFF) << 24);
  }
}

// ===== SpMM2: wave-per-node, batch-16 clamped epochs, nt int8 gathers (2 lines/row) ==
__global__ __launch_bounds__(256) void k_spmm2(
    const int* __restrict__ rowptr, const int2* __restrict__ sedge,
    const unsigned char* __restrict__ qmat,
    const float* __restrict__ Aq, const float* __restrict__ C,
    int n, int nwaves, float* __restrict__ out,
    float* __restrict__ gsum, float* __restrict__ gsq) {
  __shared__ float red[2][4][64][2];
  int t = threadIdx.x;
  int l = t & 63, wv = t >> 6;
  int gwid = blockIdx.x * 4 + wv;
  float A0 = Aq[l * 2], A1 = Aq[l * 2 + 1], C0 = C[l * 2], C1 = C[l * 2 + 1];
  float ps0 = 0, ps1 = 0, q0s = 0, q1s = 0;
  for (int node = gwid; node < n; node += nwaves) {
    int nd = __builtin_amdgcn_readfirstlane(node);
    int p0 = rowptr[nd], p1 = rowptr[nd + 1];
    float wsum = 0.f, a0 = 0.f, a1 = 0.f;
    for (int base = p0; base < p1; base += 16) {
      int2 b[16]; float w[16]; unsigned short u[16];
#pragma unroll
      for (int k = 0; k < 16; ++k) {
        int idx = base + k;
        b[k] = sedge[idx < p1 ? idx : p1 - 1];
      }
#pragma unroll
      for (int k = 0; k < 16; ++k)
        u[k] = __builtin_nontemporal_load(
            (const unsigned short*)&qmat[(size_t)(b[k].x & 0x1FFFF) * 128 + l * 2]);
#pragma unroll
      for (int k = 0; k < 16; ++k)
        w[k] = (base + k < p1) ? __int_as_float(b[k].y) : 0.f;
#pragma unroll
      for (int k = 0; k < 16; ++k) {
        wsum += w[k];
        float y0 = fmaxf(fmaf(A0, (float)(signed char)(u[k] & 0xFF), C0), 0.f);
        float y1 = fmaxf(fmaf(A1, (float)(signed char)(u[k] >> 8), C1), 0.f);
        a0 = fmaf(w[k], y0, a0);
        a1 = fmaf(w[k], y1, a1);
      }
    }
    float d = (wsum < 0.5f) ? wsum + 1.0f : wsum;
    float invd = 1.0f / d;
    a0 *= invd; a1 *= invd;
    *(float2*)&out[(size_t)node * HID + l * 2] = make_float2(a0, a1);
    ps0 += a0; ps1 += a1; q0s += a0 * a0; q1s += a1 * a1;
  }
  red[0][wv][l][0] = ps0; red[0][wv][l][1] = ps1;
  red[1][wv][l][0] = q0s; red[1][wv][l][1] = q1s;
  __syncthreads();
  if (wv == 0) {
    float s0 = 0, s1 = 0, t0 = 0, t1 = 0;
#pragma unroll
    for (int k = 0; k < 4; ++k) {
      s0 += red[0][k][l][0]; s1 += red[0][k][l][1];
      t0 += red[1][k][l][0]; t1 += red[1][k][l][1];
    }
    atomicAdd(&gsum[l * 2], s0); atomicAdd(&gsum[l * 2 + 1], s1);
    atomicAdd(&gsq[l * 2], t0);  atomicAdd(&gsq[l * 2 + 1], t1);
  }
}

// ---------------- final in-place affine on d_out ----------------
__global__ void k_final(float* __restrict__ out, const float* __restrict__ A,
                        const float* __restrict__ C, int n) {
  __shared__ float la[HID], lc[HID];
  if (threadIdx.x < HID) { la[threadIdx.x] = A[threadIdx.x]; lc[threadIdx.x] = C[threadIdx.x]; }
  __syncthreads();
  int total = n * 32;  // float4 count
  for (int i = blockIdx.x * blockDim.x + threadIdx.x; i < total; i += gridDim.x * blockDim.x) {
    float4 v = *(float4*)(out + (size_t)i * 4);
    int cg = (i & 31) * 4;
    v.x = fmaf(la[cg + 0], v.x, lc[cg + 0]);
    v.y = fmaf(la[cg + 1], v.y, lc[cg + 1]);
    v.z = fmaf(la[cg + 2], v.z, lc[cg + 2]);
    v.w = fmaf(la[cg + 3], v.w, lc[cg + 3]);
    *(float4*)(out + (size_t)i * 4) = v;
  }
}

extern "C" void kernel_launch(void* const* d_in, const int* in_sizes, int n_in,
                              void* d_out, int out_size, void* d_ws, size_t ws_size,
                              hipStream_t stream) {
  const int* x = (const int*)d_in[0];
  const int* ei = (const int*)d_in[1];
  const float* ew = (const float*)d_in[2];
  const float* emb = (const float*)d_in[3];
  const float* gw = (const float*)d_in[4];
  const float* gb = (const float*)d_in[5];
  const float* gms = (const float*)d_in[6];
  float* out = (float*)d_out;

  const int n = in_sizes[0];        // 100000
  const int e = in_sizes[1] / 2;    // 1600000
  const int* row = ei;
  const int* col = ei + e;

  // workspace layout, in 4-byte units, 128B-aligned chunks
  float* wsf = (float*)d_ws;
  size_t o = 0;
  auto alloc = [&](size_t elems) -> size_t { size_t r = o; o += ((elems + 31) & ~(size_t)31); return r; };
  size_t cnt_o = alloc(n + 1);
  size_t hist_o = alloc(65);
  size_t sum2_o = alloc(HID), sq2_o = alloc(HID), sum4_o = alloc(HID), sq4_o = alloc(HID);
  size_t hmax_o = alloc(HID);
  size_t zero_end = o;                       // everything above must be zeroed
  size_t A12_o = alloc(HID), C12_o = alloc(HID), A34_o = alloc(HID), C34_o = alloc(HID);
  size_t Aq_o = alloc(HID), qinv_o = alloc(HID);
  size_t rowptr_o = alloc(n + 1);
  size_t slot_o = alloc(e);
  size_t bsum_o = alloc(64);
  size_t emb1b_o = alloc(65 * HID / 2);      // bf16 pairs
  size_t sedge_o = alloc((size_t)e * 2);     // int2 per edge
  size_t h2b_o = alloc((size_t)n * HID / 2); // bf16 pairs (uint) per 2 elements
  size_t qmat_o = alloc((size_t)n * HID / 4); // int8 per element (uint per 4)

  int* cnt = (int*)(wsf + cnt_o);
  int* hist = (int*)(wsf + hist_o);
  float* sum2 = wsf + sum2_o; float* sq2 = wsf + sq2_o;
  float* sum4 = wsf + sum4_o; float* sq4 = wsf + sq4_o;
  unsigned* hmax = (unsigned*)(wsf + hmax_o);
  float* A12 = wsf + A12_o; float* C12 = wsf + C12_o;
  float* A34 = wsf + A34_o; float* C34 = wsf + C34_o;
  float* Aq = wsf + Aq_o; float* qinv = wsf + qinv_o;
  int* rowptr = (int*)(wsf + rowptr_o);
  int* slot = (int*)(wsf + slot_o);
  int* bsum = (int*)(wsf + bsum_o);
  unsigned* emb1b = (unsigned*)(wsf + emb1b_o);
  int2* sedge = (int2*)(wsf + sedge_o);
  unsigned* h2b = (unsigned*)(wsf + h2b_o);
  unsigned* qmat = (unsigned*)(wsf + qmat_o);

  const float invN = 1.0f / (float)n;
  const int nblk = 2048;
  const int nwaves = nblk * 4;

  hipMemsetAsync(d_ws, 0, zero_end * sizeof(float), stream);
  k_histcnt<<<2048, 256, 0, stream>>>(x, n, row, e, hist, cnt, slot);
  int nb = (n + 1 + 2047) / 2048;
  k_scan_partial<<<nb, 256, 0, stream>>>(cnt, n + 1, bsum);
  k_scan_bsum<<<1, 64, 0, stream>>>(bsum, nb);
  k_scan_final<<<nb, 256, 0, stream>>>(cnt, n + 1, bsum, rowptr);
  k_scatter<<<2048, 256, 0, stream>>>(row, col, ew, x, rowptr, slot, e, sedge);
  k_gn0<<<1, 64, 0, stream>>>(emb, hist, gw, gb, gms, invN, emb1b);
  k_spmm1<<<nblk, 256, 0, stream>>>(rowptr, sedge, emb1b, n, nwaves, h2b, sum2, sq2, hmax);
  k_gnchain<<<1, HID, 0, stream>>>(sum2, sq2, invN, gw, gb, gms, 1, 2, A12, C12,
                                   (const float*)hmax, Aq, qinv);
  k_quant<<<2048, 256, 0, stream>>>(h2b, qinv, n, qmat);
  k_spmm2<<<nblk, 256, 0, stream>>>(rowptr, sedge, (const unsigned char*)qmat, Aq, C12,
                                    n, nwaves, out, sum4, sq4);
  k_gnchain<<<1, HID, 0, stream>>>(sum4, sq4, invN, gw, gb, gms, 3, 4, A34, C34,
                                   nullptr, nullptr, nullptr);
  k_final<<<2048, 256, 0, stream>>>(out, A34, C34, n);
}